// Round 1
// baseline (6385.952 us; speedup 1.0000x reference)
//
#include <hip/hip_runtime.h>
#include <math.h>

// Problem constants
#define CL 2
#define CH 12
#define CD 768
#define CDH 64
#define CF 3072
#define CB 2
#define CT 2048

typedef __bf16 bf16x8 __attribute__((ext_vector_type(8)));
typedef float f32x4 __attribute__((ext_vector_type(4)));

__device__ __forceinline__ ushort f2bf(float f) {
  unsigned u = __float_as_uint(f);
  return (ushort)((u + 0x7fffu + ((u >> 16) & 1u)) >> 16);
}

__device__ __forceinline__ float wred_sum(float v) {
#pragma unroll
  for (int o = 32; o > 0; o >>= 1) v += __shfl_xor(v, o);
  return v;
}
__device__ __forceinline__ float wred_max(float v) {
#pragma unroll
  for (int o = 32; o > 0; o >>= 1) v = fmaxf(v, __shfl_xor(v, o));
  return v;
}

// ---------------- GEMM ----------------
// C(MxN) = A(MxK) @ B, A bf16 row-major (lda), B bf16:
//   BT=true : B stored (N x K) row-major (ldb)  -> fast LDS path
//   BT=false: B stored (K x N) row-major (ldb)  -> scatter LDS path
// M must be a multiple of 128; K a multiple of 32. N guarded.
enum { EPI_F32 = 0, EPI_BF16 = 1, EPI_BIAS_BF16 = 2, EPI_BIAS_GELU_BF16 = 3, EPI_BIAS_RES_F32 = 4 };

template <int EPI, bool BT>
__global__ __launch_bounds__(256) void gemm_k(
    const ushort* __restrict__ A, int lda,
    const ushort* __restrict__ B, int ldb,
    void* __restrict__ Cv, int ldc,
    int M, int N, int K,
    const float* __restrict__ bias,
    const float* __restrict__ res) {
  __shared__ ushort As[128][40];
  __shared__ ushort Bs[128][40];
  const int tid = threadIdx.x;
  const int lane = tid & 63;
  const int wave = tid >> 6;
  const int wm = (wave >> 1) * 64;
  const int wn = (wave & 1) * 64;
  const int m0 = blockIdx.y * 128;
  const int n0 = blockIdx.x * 128;
  const int lr = lane & 15;
  const int lg = lane >> 4;
  f32x4 acc[4][4] = {};

  for (int k0 = 0; k0 < K; k0 += 32) {
    __syncthreads();
// stage A tile (128x32)
#pragma unroll
    for (int p = 0; p < 2; ++p) {
      int i = p * 2048 + tid * 8;
      int r = i >> 5, c = i & 31;
      uint4 v = *(const uint4*)(A + (size_t)(m0 + r) * lda + k0 + c);
      *(uint4*)(&As[r][c]) = v;
    }
// stage B tile into Bs[n][k]
    if (BT) {
#pragma unroll
      for (int p = 0; p < 2; ++p) {
        int i = p * 2048 + tid * 8;
        int r = i >> 5, c = i & 31;
        uint4 v = make_uint4(0u, 0u, 0u, 0u);
        if (n0 + r < N) v = *(const uint4*)(B + (size_t)(n0 + r) * ldb + k0 + c);
        *(uint4*)(&Bs[r][c]) = v;
      }
    } else {
#pragma unroll
      for (int p = 0; p < 2; ++p) {
        int i = p * 2048 + tid * 8;
        int k = i >> 7, n = i & 127;
        uint4 v = make_uint4(0u, 0u, 0u, 0u);
        if (n0 + n < N) v = *(const uint4*)(B + (size_t)(k0 + k) * ldb + n0 + n);
        const ushort* pu = (const ushort*)&v;
#pragma unroll
        for (int j = 0; j < 8; ++j) Bs[n + j][k] = pu[j];
      }
    }
    __syncthreads();

    bf16x8 af[4], bfr[4];
#pragma unroll
    for (int f = 0; f < 4; ++f) af[f] = *(const bf16x8*)(&As[wm + f * 16 + lr][lg * 8]);
#pragma unroll
    for (int f = 0; f < 4; ++f) bfr[f] = *(const bf16x8*)(&Bs[wn + f * 16 + lr][lg * 8]);
#pragma unroll
    for (int i = 0; i < 4; ++i)
#pragma unroll
      for (int j = 0; j < 4; ++j)
        acc[i][j] = __builtin_amdgcn_mfma_f32_16x16x32_bf16(af[i], bfr[j], acc[i][j], 0, 0, 0);
  }

  // epilogue: lane holds D[row=(lane>>4)*4+r][col=lane&15] per frag
  const int cr0 = lg * 4;
#pragma unroll
  for (int i = 0; i < 4; ++i) {
#pragma unroll
    for (int j = 0; j < 4; ++j) {
      int col = n0 + wn + j * 16 + lr;
      if (col >= N) continue;
#pragma unroll
      for (int r = 0; r < 4; ++r) {
        int row = m0 + wm + i * 16 + cr0 + r;
        float val = acc[i][j][r];
        size_t offc = (size_t)row * ldc + col;
        if constexpr (EPI == EPI_F32) {
          ((float*)Cv)[offc] = val;
        } else if constexpr (EPI == EPI_BF16) {
          ((ushort*)Cv)[offc] = f2bf(val);
        } else if constexpr (EPI == EPI_BIAS_BF16) {
          ((ushort*)Cv)[offc] = f2bf(val + bias[col]);
        } else if constexpr (EPI == EPI_BIAS_GELU_BF16) {
          float x = val + bias[col];
          float gel = 0.5f * x * (1.0f + erff(x * 0.70710678118654752f));
          ((ushort*)Cv)[offc] = f2bf(gel);
        } else {
          ((float*)Cv)[offc] = val + bias[col] + res[offc];
        }
      }
    }
  }
}

// ---------------- softmax (per row of one (b,h) score tile) ----------------
__global__ __launch_bounds__(256) void softmax_k(const float* __restrict__ S,
                                                 ushort* __restrict__ P,
                                                 const int* __restrict__ mask) {
  const int t = blockIdx.x;
  const int tid = threadIdx.x;
  const float* row = S + (size_t)t * CT;
  const int* mrow = mask + (size_t)t * CT;
  float v[8];
  float mx = -INFINITY;
#pragma unroll
  for (int j = 0; j < 8; ++j) {
    int c = tid + j * 256;
    float x = row[c] * 0.125f;
    if (mrow[c] == 0) x = -INFINITY;
    v[j] = x;
    mx = fmaxf(mx, x);
  }
  mx = wred_max(mx);
  __shared__ float shm[4], shs[4];
  if ((tid & 63) == 0) shm[tid >> 6] = mx;
  __syncthreads();
  mx = fmaxf(fmaxf(shm[0], shm[1]), fmaxf(shm[2], shm[3]));
  float s = 0.f;
  float e[8];
#pragma unroll
  for (int j = 0; j < 8; ++j) {
    e[j] = expf(v[j] - mx);
    s += e[j];
  }
  s = wred_sum(s);
  if ((tid & 63) == 0) shs[tid >> 6] = s;
  __syncthreads();
  s = shs[0] + shs[1] + shs[2] + shs[3];
  float inv = 1.0f / s;
#pragma unroll
  for (int j = 0; j < 8; ++j) {
    int c = tid + j * 256;
    P[(size_t)t * CT + c] = f2bf(e[j] * inv);
  }
}

// ---------------- layernorm ----------------
__global__ __launch_bounds__(256) void ln_k(const float* __restrict__ X,
                                            ushort* __restrict__ H,
                                            const float* __restrict__ g,
                                            const float* __restrict__ b) {
  const int t = blockIdx.x;
  const int tid = threadIdx.x;
  const float* row = X + (size_t)t * CD;
  float x0 = row[tid], x1 = row[tid + 256], x2 = row[tid + 512];
  float s = wred_sum(x0 + x1 + x2);
  __shared__ float sh[4], sh2[4];
  if ((tid & 63) == 0) sh[tid >> 6] = s;
  __syncthreads();
  float mu = (sh[0] + sh[1] + sh[2] + sh[3]) * (1.0f / 768.0f);
  float d0 = x0 - mu, d1 = x1 - mu, d2 = x2 - mu;
  float vs = wred_sum(d0 * d0 + d1 * d1 + d2 * d2);
  if ((tid & 63) == 0) sh2[tid >> 6] = vs;
  __syncthreads();
  float var = (sh2[0] + sh2[1] + sh2[2] + sh2[3]) * (1.0f / 768.0f);
  float r = 1.0f / sqrtf(var + 1e-5f);
  H[(size_t)t * CD + tid] = f2bf(d0 * r * g[tid] + b[tid]);
  H[(size_t)t * CD + tid + 256] = f2bf(d1 * r * g[tid + 256] + b[tid + 256]);
  H[(size_t)t * CD + tid + 512] = f2bf(d2 * r * g[tid + 512] + b[tid + 512]);
}

// ---------------- conversions / repacks ----------------
__global__ void f32_to_bf16_k(const float* __restrict__ in, ushort* __restrict__ out, int n4) {
  int i = blockIdx.x * 256 + threadIdx.x;
  if (i >= n4) return;
  float4 f = *(const float4*)(in + (size_t)i * 4);
  ushort4 u;
  u.x = f2bf(f.x); u.y = f2bf(f.y); u.z = f2bf(f.z); u.w = f2bf(f.w);
  *(ushort4*)(out + (size_t)i * 4) = u;
}

// Wq/Wk/Wv (L,H,D,DH) -> wqkv_t (L, 2304, 768) = [l][n=sec*768+h*64+e][k=d]
__global__ void repack_qkvw_k(const float* __restrict__ Wq, const float* __restrict__ Wk,
                              const float* __restrict__ Wv, ushort* __restrict__ dst) {
  int idx = blockIdx.x * 256 + threadIdx.x;
  if (idx >= CL * 2304 * CD) return;
  int l = idx / (2304 * CD);
  int rem = idx % (2304 * CD);
  int c = rem / CD;
  int d = rem % CD;
  int sec = c / CD;
  int within = c % CD;
  int h = within / CDH;
  int e = within % CDH;
  const float* W = (sec == 0) ? Wq : ((sec == 1) ? Wk : Wv);
  float v = W[(((size_t)l * CH + h) * CD + d) * CDH + e];
  dst[idx] = f2bf(v);
}

// Wo (L, H*DH, D) -> wo_t (L, D, H*DH) = [l][n=d2][k=hd]
__global__ void repack_wo_k(const float* __restrict__ Wo, ushort* __restrict__ dst) {
  int idx = blockIdx.x * 256 + threadIdx.x;
  if (idx >= CL * CD * CD) return;
  int l = idx / (CD * CD);
  int rem = idx % (CD * CD);
  int n = rem / CD;
  int k = rem % CD;
  dst[idx] = f2bf(Wo[((size_t)l * CD + k) * CD + n]);
}

// W1 (L, D, F) -> w1_t (L, F, D)
__global__ void repack_w1_k(const float* __restrict__ W1, ushort* __restrict__ dst) {
  int idx = blockIdx.x * 256 + threadIdx.x;
  if (idx >= CL * CF * CD) return;
  int l = idx / (CF * CD);
  int rem = idx % (CF * CD);
  int f = rem / CD;
  int d = rem % CD;
  dst[idx] = f2bf(W1[((size_t)l * CD + d) * CF + f]);
}

// W2 (L, F, D) -> w2_t (L, D, F)
__global__ void repack_w2_k(const float* __restrict__ W2, ushort* __restrict__ dst) {
  int idx = blockIdx.x * 256 + threadIdx.x;
  if (idx >= CL * CD * CF) return;
  int l = idx / (CD * CF);
  int rem = idx % (CD * CF);
  int d = rem / CF;
  int f = rem % CF;
  dst[idx] = f2bf(W2[((size_t)l * CF + f) * CD + d]);
}

// bq/bk/bv (L,H,DH) -> bqkv (L, 2304) fp32
__global__ void repack_bqkv_k(const float* __restrict__ bq, const float* __restrict__ bk,
                              const float* __restrict__ bv, float* __restrict__ dst) {
  int idx = blockIdx.x * 256 + threadIdx.x;
  if (idx >= CL * 2304) return;
  int l = idx / 2304;
  int c = idx % 2304;
  int sec = c / CD;
  int within = c % CD;
  int h = within / CDH;
  int e = within % CDH;
  const float* B = (sec == 0) ? bq : ((sec == 1) ? bk : bv);
  dst[idx] = B[((size_t)l * CH + h) * CDH + e];
}

extern "C" void kernel_launch(void* const* d_in, const int* in_sizes, int n_in,
                              void* d_out, int out_size, void* d_ws, size_t ws_size,
                              hipStream_t stream) {
  (void)in_sizes; (void)n_in; (void)out_size; (void)ws_size;
  const float* X = (const float*)d_in[0];
  const int* MSK = (const int*)d_in[1];
  const float* Wq = (const float*)d_in[2];
  const float* bq = (const float*)d_in[3];
  const float* Wk = (const float*)d_in[4];
  const float* bk = (const float*)d_in[5];
  const float* Wv = (const float*)d_in[6];
  const float* bv = (const float*)d_in[7];
  const float* Wo = (const float*)d_in[8];
  const float* bo = (const float*)d_in[9];
  const float* lng = (const float*)d_in[10];
  const float* lnb = (const float*)d_in[11];
  const float* W1 = (const float*)d_in[12];
  const float* b1 = (const float*)d_in[13];
  const float* W2 = (const float*)d_in[14];
  const float* b2 = (const float*)d_in[15];

  char* base = (char*)d_ws;
  size_t off = 0;
  auto alloc = [&](size_t bytes) {
    char* p = base + off;
    off = (off + bytes + 255) & ~(size_t)255;
    return p;
  };
  ushort* wqkv_t = (ushort*)alloc((size_t)CL * 2304 * CD * 2);
  ushort* wo_t = (ushort*)alloc((size_t)CL * CD * CD * 2);
  ushort* w1_t = (ushort*)alloc((size_t)CL * CF * CD * 2);
  ushort* w2_t = (ushort*)alloc((size_t)CL * CD * CF * 2);
  float* bqkv = (float*)alloc((size_t)CL * 2304 * 4);
  ushort* xb = (ushort*)alloc((size_t)CB * CT * CD * 2);
  ushort* qkv = (ushort*)alloc((size_t)CB * CT * 2304 * 2);
  float* Sbuf = (float*)alloc((size_t)CT * CT * 4);
  ushort* Pbuf = (ushort*)alloc((size_t)CT * CT * 2);
  ushort* attno = (ushort*)alloc((size_t)CB * CT * CD * 2);
  float* xattn = (float*)alloc((size_t)CB * CT * CD * 4);
  float* xf = (float*)alloc((size_t)CB * CT * CD * 4);
  ushort* hln = (ushort*)alloc((size_t)CB * CT * CD * 2);
  ushort* gbuf = (ushort*)alloc((size_t)CB * CT * CF * 2);

  const int BT_ = CB * CT;  // 4096 rows

  // weight repacks
  {
    int n = CL * 2304 * CD;
    repack_qkvw_k<<<(n + 255) / 256, 256, 0, stream>>>(Wq, Wk, Wv, wqkv_t);
  }
  {
    int n = CL * CD * CD;
    repack_wo_k<<<(n + 255) / 256, 256, 0, stream>>>(Wo, wo_t);
  }
  {
    int n = CL * CF * CD;
    repack_w1_k<<<(n + 255) / 256, 256, 0, stream>>>(W1, w1_t);
    repack_w2_k<<<(n + 255) / 256, 256, 0, stream>>>(W2, w2_t);
  }
  {
    int n = CL * 2304;
    repack_bqkv_k<<<(n + 255) / 256, 256, 0, stream>>>(bq, bk, bv, bqkv);
  }

  for (int l = 0; l < CL; ++l) {
    const float* xcur = (l == 0) ? X : xf;
    // x -> bf16
    {
      int n4 = BT_ * CD / 4;
      f32_to_bf16_k<<<(n4 + 255) / 256, 256, 0, stream>>>(xcur, xb, n4);
    }
    // QKV projection: (4096x768) @ (768x2304) + bias -> qkv bf16
    gemm_k<EPI_BIAS_BF16, true><<<dim3(2304 / 128, BT_ / 128), 256, 0, stream>>>(
        xb, CD, wqkv_t + (size_t)l * 2304 * CD, CD, qkv, 2304, BT_, 2304, CD,
        bqkv + (size_t)l * 2304, nullptr);
    // attention per (b,h)
    for (int b = 0; b < CB; ++b) {
      for (int h = 0; h < CH; ++h) {
        const ushort* Qv = qkv + (size_t)b * CT * 2304 + h * CDH;
        const ushort* Kv = Qv + CD;
        const ushort* Vv = Qv + 2 * CD;
        gemm_k<EPI_F32, true><<<dim3(CT / 128, CT / 128), 256, 0, stream>>>(
            Qv, 2304, Kv, 2304, Sbuf, CT, CT, CT, CDH, nullptr, nullptr);
        softmax_k<<<CT, 256, 0, stream>>>(Sbuf, Pbuf, MSK);
        gemm_k<EPI_BF16, false><<<dim3(1, CT / 128), 256, 0, stream>>>(
            Pbuf, CT, Vv, 2304, attno + (size_t)b * CT * CD + h * CDH, CD,
            CT, CDH, CT, nullptr, nullptr);
      }
    }
    // output projection + bias + residual -> xattn (fp32)
    gemm_k<EPI_BIAS_RES_F32, true><<<dim3(CD / 128, BT_ / 128), 256, 0, stream>>>(
        attno, CD, wo_t + (size_t)l * CD * CD, CD, xattn, CD, BT_, CD, CD,
        bo + (size_t)l * CD, xcur);
    // layernorm -> hln bf16
    ln_k<<<BT_, 256, 0, stream>>>(xattn, hln, lng + (size_t)l * CD, lnb + (size_t)l * CD);
    // FFN1 + bias + gelu -> gbuf bf16
    gemm_k<EPI_BIAS_GELU_BF16, true><<<dim3(CF / 128, BT_ / 128), 256, 0, stream>>>(
        hln, CD, w1_t + (size_t)l * CF * CD, CD, gbuf, CF, BT_, CF, CD,
        b1 + (size_t)l * CF, nullptr);
    // FFN2 + bias + residual -> xf (or d_out on last layer), fp32
    float* dst = (l == CL - 1) ? (float*)d_out : xf;
    gemm_k<EPI_BIAS_RES_F32, true><<<dim3(CD / 128, BT_ / 128), 256, 0, stream>>>(
        gbuf, CF, w2_t + (size_t)l * CD * CF, CF, dst, CD, BT_, CD, CF,
        b2 + (size_t)l * CD, xattn);
  }
}

// Round 2
// 715.775 us; speedup vs baseline: 8.9217x; 8.9217x over previous
//
#include <hip/hip_runtime.h>
#include <math.h>

// Problem constants
#define CL 2
#define CH 12
#define CD 768
#define CDH 64
#define CF 3072
#define CB 2
#define CT 2048

typedef __bf16 bf16x8 __attribute__((ext_vector_type(8)));
typedef float f32x4 __attribute__((ext_vector_type(4)));

__device__ __forceinline__ ushort f2bf(float f) {
  unsigned u = __float_as_uint(f);
  return (ushort)((u + 0x7fffu + ((u >> 16) & 1u)) >> 16);
}

__device__ __forceinline__ float wred_sum(float v) {
#pragma unroll
  for (int o = 32; o > 0; o >>= 1) v += __shfl_xor(v, o);
  return v;
}
__device__ __forceinline__ float wred_max(float v) {
#pragma unroll
  for (int o = 32; o > 0; o >>= 1) v = fmaxf(v, __shfl_xor(v, o));
  return v;
}

// ---------------- GEMM ----------------
// C(MxN) = A(MxK) @ B, A bf16 row-major (lda), B stored (N x K) row-major (ldb).
// M must be a multiple of 128; K a multiple of 32. N guarded.
enum { EPI_F32 = 0, EPI_BF16 = 1, EPI_BIAS_BF16 = 2, EPI_BIAS_GELU_BF16 = 3, EPI_BIAS_RES_F32 = 4 };

template <int EPI>
__global__ __launch_bounds__(256) void gemm_k(
    const ushort* __restrict__ A, int lda,
    const ushort* __restrict__ B, int ldb,
    void* __restrict__ Cv, int ldc,
    int M, int N, int K,
    const float* __restrict__ bias,
    const float* __restrict__ res) {
  __shared__ ushort As[128][40];
  __shared__ ushort Bs[128][40];
  const int tid = threadIdx.x;
  const int lane = tid & 63;
  const int wave = tid >> 6;
  const int wm = (wave >> 1) * 64;
  const int wn = (wave & 1) * 64;
  const int m0 = blockIdx.y * 128;
  const int n0 = blockIdx.x * 128;
  const int lr = lane & 15;
  const int lg = lane >> 4;
  f32x4 acc[4][4] = {};

  for (int k0 = 0; k0 < K; k0 += 32) {
    __syncthreads();
#pragma unroll
    for (int p = 0; p < 2; ++p) {
      int i = p * 2048 + tid * 8;
      int r = i >> 5, c = i & 31;
      uint4 v = *(const uint4*)(A + (size_t)(m0 + r) * lda + k0 + c);
      *(uint4*)(&As[r][c]) = v;
    }
#pragma unroll
    for (int p = 0; p < 2; ++p) {
      int i = p * 2048 + tid * 8;
      int r = i >> 5, c = i & 31;
      uint4 v = make_uint4(0u, 0u, 0u, 0u);
      if (n0 + r < N) v = *(const uint4*)(B + (size_t)(n0 + r) * ldb + k0 + c);
      *(uint4*)(&Bs[r][c]) = v;
    }
    __syncthreads();

    bf16x8 af[4], bfr[4];
#pragma unroll
    for (int f = 0; f < 4; ++f) af[f] = *(const bf16x8*)(&As[wm + f * 16 + lr][lg * 8]);
#pragma unroll
    for (int f = 0; f < 4; ++f) bfr[f] = *(const bf16x8*)(&Bs[wn + f * 16 + lr][lg * 8]);
#pragma unroll
    for (int i = 0; i < 4; ++i)
#pragma unroll
      for (int j = 0; j < 4; ++j)
        acc[i][j] = __builtin_amdgcn_mfma_f32_16x16x32_bf16(af[i], bfr[j], acc[i][j], 0, 0, 0);
  }

  const int cr0 = lg * 4;
#pragma unroll
  for (int i = 0; i < 4; ++i) {
#pragma unroll
    for (int j = 0; j < 4; ++j) {
      int col = n0 + wn + j * 16 + lr;
      if (col >= N) continue;
#pragma unroll
      for (int r = 0; r < 4; ++r) {
        int row = m0 + wm + i * 16 + cr0 + r;
        float val = acc[i][j][r];
        size_t offc = (size_t)row * ldc + col;
        if constexpr (EPI == EPI_F32) {
          ((float*)Cv)[offc] = val;
        } else if constexpr (EPI == EPI_BF16) {
          ((ushort*)Cv)[offc] = f2bf(val);
        } else if constexpr (EPI == EPI_BIAS_BF16) {
          ((ushort*)Cv)[offc] = f2bf(val + bias[col]);
        } else if constexpr (EPI == EPI_BIAS_GELU_BF16) {
          float x = val + bias[col];
          float gel = 0.5f * x * (1.0f + erff(x * 0.70710678118654752f));
          ((ushort*)Cv)[offc] = f2bf(gel);
        } else {
          ((float*)Cv)[offc] = val + bias[col] + res[offc];
        }
      }
    }
  }
}

// ---------------- flash attention ----------------
// grid: (CT/64, CB*CH). block 256 = 4 waves; each wave owns 16 q rows.
// qkv: [B*T][2304] bf16 (Q at +0, K at +768, V at +1536, head h at h*64)
// vt:  [B*H][64][2048] bf16 (V transposed per (b,h): [e][t])
// mbits: [T][64] uint32 bitmask of attn_mask row
// out: attno [B*T][768] bf16
__global__ __launch_bounds__(256) void flash_k(const ushort* __restrict__ qkv,
                                               const ushort* __restrict__ vt,
                                               const unsigned* __restrict__ mbits,
                                               ushort* __restrict__ out) {
  const int q0 = blockIdx.x * 64;
  const int bh = blockIdx.y;
  const int b = bh / CH, h = bh % CH;
  const int tid = threadIdx.x;
  const int lane = tid & 63;
  const int wave = tid >> 6;
  const int lr = lane & 15;
  const int lg = lane >> 4;

  __shared__ ushort Ks[64][72];
  __shared__ ushort Vs[64][72];
  __shared__ ushort Ps[4][16][72];

  // Q fragments: A row = lr, k = kf*32 + lg*8
  const ushort* qrow = qkv + ((size_t)(b * CT) + q0 + wave * 16 + lr) * 2304 + h * CDH;
  bf16x8 aq0 = *(const bf16x8*)(qrow + lg * 8);
  bf16x8 aq1 = *(const bf16x8*)(qrow + 32 + lg * 8);

  f32x4 acc[4] = {};
  float mrow[4] = {-1e30f, -1e30f, -1e30f, -1e30f};
  float lrow[4] = {};

  const ushort* kbase = qkv + (size_t)(b * CT) * 2304 + CD + h * CDH;
  const ushort* vbase = vt + (size_t)bh * 64 * CT;

  for (int kv0 = 0; kv0 < CT; kv0 += 64) {
    __syncthreads();
#pragma unroll
    for (int p = 0; p < 2; ++p) {
      int i = p * 2048 + tid * 8;
      int r = i >> 6, c = i & 63;
      *(bf16x8*)(&Ks[r][c]) = *(const bf16x8*)(kbase + (size_t)(kv0 + r) * 2304 + c);
      *(bf16x8*)(&Vs[r][c]) = *(const bf16x8*)(vbase + (size_t)r * CT + kv0 + c);
    }
    __syncthreads();

    // S = Q K^T  (wave tile: 16 q rows x 64 kv cols)
    f32x4 s[4] = {};
#pragma unroll
    for (int j = 0; j < 4; ++j) {
      bf16x8 bk0 = *(const bf16x8*)(&Ks[j * 16 + lr][lg * 8]);
      bf16x8 bk1 = *(const bf16x8*)(&Ks[j * 16 + lr][32 + lg * 8]);
      s[j] = __builtin_amdgcn_mfma_f32_16x16x32_bf16(aq0, bk0, s[j], 0, 0, 0);
      s[j] = __builtin_amdgcn_mfma_f32_16x16x32_bf16(aq1, bk1, s[j], 0, 0, 0);
    }

    // scale + mask + online softmax; C layout: row=lg*4+r, col=j*16+lr
#pragma unroll
    for (int r = 0; r < 4; ++r) {
      int qrow_g = q0 + wave * 16 + lg * 4 + r;
      unsigned w0 = mbits[(size_t)qrow_g * 64 + (kv0 >> 5)];
      unsigned w1 = mbits[(size_t)qrow_g * 64 + (kv0 >> 5) + 1];
#pragma unroll
      for (int j = 0; j < 4; ++j) {
        float x = s[j][r] * 0.125f;
        unsigned w = (j < 2) ? w0 : w1;
        int bit = (j * 16 + lr) & 31;
        if (((w >> bit) & 1u) == 0u) x = -INFINITY;
        s[j][r] = x;
      }
      float mx = fmaxf(fmaxf(s[0][r], s[1][r]), fmaxf(s[2][r], s[3][r]));
#pragma unroll
      for (int d = 1; d < 16; d <<= 1) mx = fmaxf(mx, __shfl_xor(mx, d));
      float mnew = fmaxf(mrow[r], mx);
      float sc = __expf(mrow[r] - mnew);
      mrow[r] = mnew;
      float sum = 0.f;
#pragma unroll
      for (int j = 0; j < 4; ++j) {
        float p = __expf(s[j][r] - mnew);
        s[j][r] = p;
        sum += p;
      }
#pragma unroll
      for (int d = 1; d < 16; d <<= 1) sum += __shfl_xor(sum, d);
      lrow[r] = lrow[r] * sc + sum;
#pragma unroll
      for (int jj = 0; jj < 4; ++jj) acc[jj][r] *= sc;
    }

    // P (C layout) -> Ps (A layout staging)
#pragma unroll
    for (int r = 0; r < 4; ++r)
#pragma unroll
      for (int j = 0; j < 4; ++j) Ps[wave][lg * 4 + r][j * 16 + lr] = f2bf(s[j][r]);

    bf16x8 pa0 = *(const bf16x8*)(&Ps[wave][lr][lg * 8]);
    bf16x8 pa1 = *(const bf16x8*)(&Ps[wave][lr][32 + lg * 8]);
#pragma unroll
    for (int jj = 0; jj < 4; ++jj) {
      bf16x8 bv0 = *(const bf16x8*)(&Vs[jj * 16 + lr][lg * 8]);
      bf16x8 bv1 = *(const bf16x8*)(&Vs[jj * 16 + lr][32 + lg * 8]);
      acc[jj] = __builtin_amdgcn_mfma_f32_16x16x32_bf16(pa0, bv0, acc[jj], 0, 0, 0);
      acc[jj] = __builtin_amdgcn_mfma_f32_16x16x32_bf16(pa1, bv1, acc[jj], 0, 0, 0);
    }
  }

  // write O = acc / l
#pragma unroll
  for (int r = 0; r < 4; ++r) {
    float inv = 1.0f / lrow[r];
    int row = b * CT + q0 + wave * 16 + lg * 4 + r;
#pragma unroll
    for (int jj = 0; jj < 4; ++jj)
      out[(size_t)row * CD + h * CDH + jj * 16 + lr] = f2bf(acc[jj][r] * inv);
  }
}

// ---------------- V transpose: qkv V section -> vt [bh][e][t] ----------------
__global__ __launch_bounds__(256) void vtrans_k(const ushort* __restrict__ qkv,
                                                ushort* __restrict__ vt) {
  const int t0 = blockIdx.x * 64;
  const int bh = blockIdx.y;
  const int b = bh / CH, h = bh % CH;
  const int tid = threadIdx.x;
  __shared__ ushort tile[64][72];
#pragma unroll
  for (int p = 0; p < 2; ++p) {
    int i = p * 2048 + tid * 8;
    int tr = i >> 6, c = i & 63;
    *(bf16x8*)(&tile[tr][c]) =
        *(const bf16x8*)(qkv + (size_t)(b * CT + t0 + tr) * 2304 + 2 * CD + h * CDH + c);
  }
  __syncthreads();
#pragma unroll
  for (int p = 0; p < 2; ++p) {
    int i = p * 2048 + tid * 8;
    int er = i >> 6, tc = i & 63;
    ushort tmp[8];
#pragma unroll
    for (int j = 0; j < 8; ++j) tmp[j] = tile[tc + j][er];
    *(bf16x8*)(vt + (size_t)bh * 64 * CT + (size_t)er * CT + t0 + tc) = *(bf16x8*)tmp;
  }
}

// ---------------- mask -> bitmask ----------------
__global__ void maskbits_k(const int* __restrict__ mask, unsigned* __restrict__ mbits) {
  int idx = blockIdx.x * 256 + threadIdx.x;
  if (idx >= CT * 64) return;
  const int* mp = mask + (size_t)(idx >> 6) * CT + (idx & 63) * 32;
  unsigned bits = 0;
#pragma unroll
  for (int j = 0; j < 32; ++j) bits |= (mp[j] != 0 ? 1u : 0u) << j;
  mbits[idx] = bits;
}

// ---------------- layernorm ----------------
__global__ __launch_bounds__(256) void ln_k(const float* __restrict__ X,
                                            ushort* __restrict__ H,
                                            const float* __restrict__ g,
                                            const float* __restrict__ b) {
  const int t = blockIdx.x;
  const int tid = threadIdx.x;
  const float* row = X + (size_t)t * CD;
  float x0 = row[tid], x1 = row[tid + 256], x2 = row[tid + 512];
  float s = wred_sum(x0 + x1 + x2);
  __shared__ float sh[4], sh2[4];
  if ((tid & 63) == 0) sh[tid >> 6] = s;
  __syncthreads();
  float mu = (sh[0] + sh[1] + sh[2] + sh[3]) * (1.0f / 768.0f);
  float d0 = x0 - mu, d1 = x1 - mu, d2 = x2 - mu;
  float vs = wred_sum(d0 * d0 + d1 * d1 + d2 * d2);
  if ((tid & 63) == 0) sh2[tid >> 6] = vs;
  __syncthreads();
  float var = (sh2[0] + sh2[1] + sh2[2] + sh2[3]) * (1.0f / 768.0f);
  float r = 1.0f / sqrtf(var + 1e-5f);
  H[(size_t)t * CD + tid] = f2bf(d0 * r * g[tid] + b[tid]);
  H[(size_t)t * CD + tid + 256] = f2bf(d1 * r * g[tid + 256] + b[tid + 256]);
  H[(size_t)t * CD + tid + 512] = f2bf(d2 * r * g[tid + 512] + b[tid + 512]);
}

// ---------------- conversions / repacks ----------------
__global__ void f32_to_bf16_k(const float* __restrict__ in, ushort* __restrict__ out, int n4) {
  int i = blockIdx.x * 256 + threadIdx.x;
  if (i >= n4) return;
  float4 f = *(const float4*)(in + (size_t)i * 4);
  ushort4 u;
  u.x = f2bf(f.x); u.y = f2bf(f.y); u.z = f2bf(f.z); u.w = f2bf(f.w);
  *(ushort4*)(out + (size_t)i * 4) = u;
}

__global__ void repack_qkvw_k(const float* __restrict__ Wq, const float* __restrict__ Wk,
                              const float* __restrict__ Wv, ushort* __restrict__ dst) {
  int idx = blockIdx.x * 256 + threadIdx.x;
  if (idx >= CL * 2304 * CD) return;
  int l = idx / (2304 * CD);
  int rem = idx % (2304 * CD);
  int c = rem / CD;
  int d = rem % CD;
  int sec = c / CD;
  int within = c % CD;
  int h = within / CDH;
  int e = within % CDH;
  const float* W = (sec == 0) ? Wq : ((sec == 1) ? Wk : Wv);
  float v = W[(((size_t)l * CH + h) * CD + d) * CDH + e];
  dst[idx] = f2bf(v);
}

__global__ void repack_wo_k(const float* __restrict__ Wo, ushort* __restrict__ dst) {
  int idx = blockIdx.x * 256 + threadIdx.x;
  if (idx >= CL * CD * CD) return;
  int l = idx / (CD * CD);
  int rem = idx % (CD * CD);
  int n = rem / CD;
  int k = rem % CD;
  dst[idx] = f2bf(Wo[((size_t)l * CD + k) * CD + n]);
}

__global__ void repack_w1_k(const float* __restrict__ W1, ushort* __restrict__ dst) {
  int idx = blockIdx.x * 256 + threadIdx.x;
  if (idx >= CL * CF * CD) return;
  int l = idx / (CF * CD);
  int rem = idx % (CF * CD);
  int f = rem / CD;
  int d = rem % CD;
  dst[idx] = f2bf(W1[((size_t)l * CD + d) * CF + f]);
}

__global__ void repack_w2_k(const float* __restrict__ W2, ushort* __restrict__ dst) {
  int idx = blockIdx.x * 256 + threadIdx.x;
  if (idx >= CL * CD * CF) return;
  int l = idx / (CD * CF);
  int rem = idx % (CD * CF);
  int d = rem / CF;
  int f = rem % CF;
  dst[idx] = f2bf(W2[((size_t)l * CF + f) * CD + d]);
}

__global__ void repack_bqkv_k(const float* __restrict__ bq, const float* __restrict__ bk,
                              const float* __restrict__ bv, float* __restrict__ dst) {
  int idx = blockIdx.x * 256 + threadIdx.x;
  if (idx >= CL * 2304) return;
  int l = idx / 2304;
  int c = idx % 2304;
  int sec = c / CD;
  int within = c % CD;
  int h = within / CDH;
  int e = within % CDH;
  const float* B = (sec == 0) ? bq : ((sec == 1) ? bk : bv);
  dst[idx] = B[((size_t)l * CH + h) * CDH + e];
}

extern "C" void kernel_launch(void* const* d_in, const int* in_sizes, int n_in,
                              void* d_out, int out_size, void* d_ws, size_t ws_size,
                              hipStream_t stream) {
  (void)in_sizes; (void)n_in; (void)out_size; (void)ws_size;
  const float* X = (const float*)d_in[0];
  const int* MSK = (const int*)d_in[1];
  const float* Wq = (const float*)d_in[2];
  const float* bq = (const float*)d_in[3];
  const float* Wk = (const float*)d_in[4];
  const float* bk = (const float*)d_in[5];
  const float* Wv = (const float*)d_in[6];
  const float* bv = (const float*)d_in[7];
  const float* Wo = (const float*)d_in[8];
  const float* bo = (const float*)d_in[9];
  const float* lng = (const float*)d_in[10];
  const float* lnb = (const float*)d_in[11];
  const float* W1 = (const float*)d_in[12];
  const float* b1 = (const float*)d_in[13];
  const float* W2 = (const float*)d_in[14];
  const float* b2 = (const float*)d_in[15];

  char* base = (char*)d_ws;
  size_t off = 0;
  auto alloc = [&](size_t bytes) {
    char* p = base + off;
    off = (off + bytes + 255) & ~(size_t)255;
    return p;
  };
  ushort* wqkv_t = (ushort*)alloc((size_t)CL * 2304 * CD * 2);
  ushort* wo_t = (ushort*)alloc((size_t)CL * CD * CD * 2);
  ushort* w1_t = (ushort*)alloc((size_t)CL * CF * CD * 2);
  ushort* w2_t = (ushort*)alloc((size_t)CL * CD * CF * 2);
  float* bqkv = (float*)alloc((size_t)CL * 2304 * 4);
  ushort* xb = (ushort*)alloc((size_t)CB * CT * CD * 2);
  ushort* qkv = (ushort*)alloc((size_t)CB * CT * 2304 * 2);
  ushort* vt = (ushort*)alloc((size_t)CB * CH * CDH * CT * 2);
  unsigned* mbits = (unsigned*)alloc((size_t)CT * 64 * 4);
  ushort* attno = (ushort*)alloc((size_t)CB * CT * CD * 2);
  float* xattn = (float*)alloc((size_t)CB * CT * CD * 4);
  float* xf = (float*)alloc((size_t)CB * CT * CD * 4);
  ushort* hln = (ushort*)alloc((size_t)CB * CT * CD * 2);
  ushort* gbuf = (ushort*)alloc((size_t)CB * CT * CF * 2);

  const int BT_ = CB * CT;  // 4096 rows

  // one-time preprocessing
  {
    int n = CL * 2304 * CD;
    repack_qkvw_k<<<(n + 255) / 256, 256, 0, stream>>>(Wq, Wk, Wv, wqkv_t);
  }
  {
    int n = CL * CD * CD;
    repack_wo_k<<<(n + 255) / 256, 256, 0, stream>>>(Wo, wo_t);
  }
  {
    int n = CL * CF * CD;
    repack_w1_k<<<(n + 255) / 256, 256, 0, stream>>>(W1, w1_t);
    repack_w2_k<<<(n + 255) / 256, 256, 0, stream>>>(W2, w2_t);
  }
  {
    int n = CL * 2304;
    repack_bqkv_k<<<(n + 255) / 256, 256, 0, stream>>>(bq, bk, bv, bqkv);
  }
  maskbits_k<<<(CT * 64 + 255) / 256, 256, 0, stream>>>(MSK, mbits);

  for (int l = 0; l < CL; ++l) {
    const float* xcur = (l == 0) ? X : xf;
    {
      int n4 = BT_ * CD / 4;
      f32_to_bf16_k<<<(n4 + 255) / 256, 256, 0, stream>>>(xcur, xb, n4);
    }
    // QKV projection: (4096x768) @ (768x2304) + bias -> qkv bf16
    gemm_k<EPI_BIAS_BF16><<<dim3(2304 / 128, BT_ / 128), 256, 0, stream>>>(
        xb, CD, wqkv_t + (size_t)l * 2304 * CD, CD, qkv, 2304, BT_, 2304, CD,
        bqkv + (size_t)l * 2304, nullptr);
    // V transpose + fused flash attention
    vtrans_k<<<dim3(CT / 64, CB * CH), 256, 0, stream>>>(qkv, vt);
    flash_k<<<dim3(CT / 64, CB * CH), 256, 0, stream>>>(qkv, vt, mbits, attno);
    // output projection + bias + residual -> xattn (fp32)
    gemm_k<EPI_BIAS_RES_F32><<<dim3(CD / 128, BT_ / 128), 256, 0, stream>>>(
        attno, CD, wo_t + (size_t)l * CD * CD, CD, xattn, CD, BT_, CD, CD,
        bo + (size_t)l * CD, xcur);
    // layernorm -> hln bf16
    ln_k<<<BT_, 256, 0, stream>>>(xattn, hln, lng + (size_t)l * CD, lnb + (size_t)l * CD);
    // FFN1 + bias + gelu -> gbuf bf16
    gemm_k<EPI_BIAS_GELU_BF16><<<dim3(CF / 128, BT_ / 128), 256, 0, stream>>>(
        hln, CD, w1_t + (size_t)l * CF * CD, CD, gbuf, CF, BT_, CF, CD,
        b1 + (size_t)l * CF, nullptr);
    // FFN2 + bias + residual -> xf (or d_out on last layer), fp32
    float* dst = (l == CL - 1) ? (float*)d_out : xf;
    gemm_k<EPI_BIAS_RES_F32><<<dim3(CD / 128, BT_ / 128), 256, 0, stream>>>(
        gbuf, CF, w2_t + (size_t)l * CD * CF, CF, dst, CD, BT_, CD, CF,
        b2 + (size_t)l * CD, xattn);
  }
}

// Round 3
// 635.548 us; speedup vs baseline: 10.0479x; 1.1262x over previous
//
#include <hip/hip_runtime.h>
#include <math.h>

// Problem constants
#define CL 2
#define CH 12
#define CD 768
#define CDH 64
#define CF 3072
#define CB 2
#define CT 2048

typedef __bf16 bf16x8 __attribute__((ext_vector_type(8)));
typedef float f32x4 __attribute__((ext_vector_type(4)));

__device__ __forceinline__ ushort f2bf(float f) {
  return __builtin_bit_cast(ushort, (__bf16)f);
}

__device__ __forceinline__ float fexp2(float x) {
  float r;
  asm volatile("v_exp_f32 %0, %1" : "=v"(r) : "v"(x));
  return r;
}

__device__ __forceinline__ float wred_sum(float v) {
#pragma unroll
  for (int o = 32; o > 0; o >>= 1) v += __shfl_xor(v, o);
  return v;
}

// async global->LDS, 16B per lane. LDS dest = wave-uniform base + lane*16.
__device__ __forceinline__ void gload16(const ushort* g, ushort* l) {
  __builtin_amdgcn_global_load_lds(
      (const __attribute__((address_space(1))) unsigned int*)g,
      (__attribute__((address_space(3))) unsigned int*)l, 16, 0, 0);
}

// ---------------- GEMM (m97 structure) ----------------
// C(MxN) = A(MxK) @ B, A bf16 row-major (lda), B stored (N x K) row-major (ldb).
// REQUIRES: M % 128 == 0, N % 128 == 0, K % 32 == 0. No bounds checks.
enum { EPI_BF16 = 1, EPI_BIAS_BF16 = 2, EPI_BIAS_GELU_BF16 = 3, EPI_BIAS_RES_F32 = 4, EPI_BIAS_RES_F32_BF16 = 5 };

template <int EPI>
__global__ __launch_bounds__(256) void gemm_k(
    const ushort* __restrict__ A, int lda,
    const ushort* __restrict__ B, int ldb,
    void* __restrict__ Cv, int ldc,
    int K,
    const float* __restrict__ bias,
    const float* __restrict__ res,
    ushort* __restrict__ C2) {
  __shared__ ushort As[128 * 32];
  __shared__ ushort Bs[128 * 32];
  const int tid = threadIdx.x;
  const int lane = tid & 63;
  const int wave = tid >> 6;
  const int wm = (wave >> 1) * 64;
  const int wn = (wave & 1) * 64;
  const int m0 = blockIdx.y * 128;
  const int n0 = blockIdx.x * 128;
  const int lr = lane & 15;
  const int lg = lane >> 4;
  f32x4 acc[4][4] = {};

  // staging: issue p covers rows p*64 + tid/4, cols (tid&3)*8
  const ushort* pa = A + (size_t)(m0 + (tid >> 2)) * lda + (tid & 3) * 8;
  const ushort* pb = B + (size_t)(n0 + (tid >> 2)) * ldb + (tid & 3) * 8;
  ushort* la = As + wave * 512;  // + p*2048
  ushort* lb = Bs + wave * 512;

  for (int k0 = 0; k0 < K; k0 += 32) {
    __syncthreads();
#pragma unroll
    for (int p = 0; p < 2; ++p) {
      gload16(pa + (size_t)p * 64 * lda + k0, la + p * 2048);
      gload16(pb + (size_t)p * 64 * ldb + k0, lb + p * 2048);
    }
    __syncthreads();

    bf16x8 af[4], bfr[4];
#pragma unroll
    for (int f = 0; f < 4; ++f) af[f] = *(const bf16x8*)(As + (wm + f * 16 + lr) * 32 + lg * 8);
#pragma unroll
    for (int f = 0; f < 4; ++f) bfr[f] = *(const bf16x8*)(Bs + (wn + f * 16 + lr) * 32 + lg * 8);
#pragma unroll
    for (int i = 0; i < 4; ++i)
#pragma unroll
      for (int j = 0; j < 4; ++j)
        acc[i][j] = __builtin_amdgcn_mfma_f32_16x16x32_bf16(af[i], bfr[j], acc[i][j], 0, 0, 0);
  }

  // epilogue: lane holds D[row=(lane>>4)*4+r][col=lane&15] per frag
  const int cr0 = lg * 4;
#pragma unroll
  for (int i = 0; i < 4; ++i) {
#pragma unroll
    for (int j = 0; j < 4; ++j) {
      int col = n0 + wn + j * 16 + lr;
#pragma unroll
      for (int r = 0; r < 4; ++r) {
        int row = m0 + wm + i * 16 + cr0 + r;
        float val = acc[i][j][r];
        size_t offc = (size_t)row * ldc + col;
        if constexpr (EPI == EPI_BF16) {
          ((ushort*)Cv)[offc] = f2bf(val);
        } else if constexpr (EPI == EPI_BIAS_BF16) {
          ((ushort*)Cv)[offc] = f2bf(val + bias[col]);
        } else if constexpr (EPI == EPI_BIAS_GELU_BF16) {
          float x = val + bias[col];
          float gel = 0.5f * x * (1.0f + erff(x * 0.70710678118654752f));
          ((ushort*)Cv)[offc] = f2bf(gel);
        } else if constexpr (EPI == EPI_BIAS_RES_F32) {
          ((float*)Cv)[offc] = val + bias[col] + res[offc];
        } else {
          float o = val + bias[col] + res[offc];
          ((float*)Cv)[offc] = o;
          C2[offc] = f2bf(o);
        }
      }
    }
  }
}

// ---------------- flash attention ----------------
// grid: (CT/64, CB*CH). block 256 = 4 waves; each wave owns 16 q rows.
__global__ __launch_bounds__(256) void flash_k(const ushort* __restrict__ qkv,
                                               const ushort* __restrict__ vt,
                                               const unsigned* __restrict__ mbits,
                                               ushort* __restrict__ out) {
  const int q0 = blockIdx.x * 64;
  const int bh = blockIdx.y;
  const int b = bh / CH, h = bh % CH;
  const int tid = threadIdx.x;
  const int lane = tid & 63;
  const int wave = tid >> 6;
  const int lr = lane & 15;
  const int lg = lane >> 4;

  __shared__ ushort Ks[64][72];
  __shared__ ushort Vs[64][72];
  __shared__ ushort Ps[4][16][72];

  const float SCL2 = 0.125f * 1.44269504088896f;  // (1/sqrt(64)) * log2(e)

  const ushort* qrow = qkv + ((size_t)(b * CT) + q0 + wave * 16 + lr) * 2304 + h * CDH;
  bf16x8 aq0 = *(const bf16x8*)(qrow + lg * 8);
  bf16x8 aq1 = *(const bf16x8*)(qrow + 32 + lg * 8);

  f32x4 acc[4] = {};
  float mrow[4] = {-1e30f, -1e30f, -1e30f, -1e30f};
  float lrow[4] = {};

  const ushort* kbase = qkv + (size_t)(b * CT) * 2304 + CD + h * CDH;
  const ushort* vbase = vt + (size_t)bh * 64 * CT;

  for (int kv0 = 0; kv0 < CT; kv0 += 64) {
    __syncthreads();
#pragma unroll
    for (int p = 0; p < 2; ++p) {
      int i = p * 2048 + tid * 8;
      int r = i >> 6, c = i & 63;
      *(bf16x8*)(&Ks[r][c]) = *(const bf16x8*)(kbase + (size_t)(kv0 + r) * 2304 + c);
      *(bf16x8*)(&Vs[r][c]) = *(const bf16x8*)(vbase + (size_t)r * CT + kv0 + c);
    }
    __syncthreads();

    // S = Q K^T  (wave tile: 16 q rows x 64 kv cols)
    f32x4 s[4] = {};
#pragma unroll
    for (int j = 0; j < 4; ++j) {
      bf16x8 bk0 = *(const bf16x8*)(&Ks[j * 16 + lr][lg * 8]);
      bf16x8 bk1 = *(const bf16x8*)(&Ks[j * 16 + lr][32 + lg * 8]);
      s[j] = __builtin_amdgcn_mfma_f32_16x16x32_bf16(aq0, bk0, s[j], 0, 0, 0);
      s[j] = __builtin_amdgcn_mfma_f32_16x16x32_bf16(aq1, bk1, s[j], 0, 0, 0);
    }

    // scale(log2 domain) + mask + online softmax; C layout: row=lg*4+r, col=j*16+lr
#pragma unroll
    for (int r = 0; r < 4; ++r) {
      int qrow_g = q0 + wave * 16 + lg * 4 + r;
      unsigned w0 = mbits[(size_t)qrow_g * 64 + (kv0 >> 5)];
      unsigned w1 = mbits[(size_t)qrow_g * 64 + (kv0 >> 5) + 1];
#pragma unroll
      for (int j = 0; j < 4; ++j) {
        float x = s[j][r] * SCL2;
        unsigned w = (j < 2) ? w0 : w1;
        int bit = (j * 16 + lr) & 31;
        if (((w >> bit) & 1u) == 0u) x = -INFINITY;
        s[j][r] = x;
      }
      float mx = fmaxf(fmaxf(s[0][r], s[1][r]), fmaxf(s[2][r], s[3][r]));
#pragma unroll
      for (int d = 1; d < 16; d <<= 1) mx = fmaxf(mx, __shfl_xor(mx, d));
      float mnew = fmaxf(mrow[r], mx);
      float sc = fexp2(mrow[r] - mnew);
      mrow[r] = mnew;
      float sum = 0.f;
#pragma unroll
      for (int j = 0; j < 4; ++j) {
        float p = fexp2(s[j][r] - mnew);
        s[j][r] = p;
        sum += p;
      }
#pragma unroll
      for (int d = 1; d < 16; d <<= 1) sum += __shfl_xor(sum, d);
      lrow[r] = lrow[r] * sc + sum;
#pragma unroll
      for (int jj = 0; jj < 4; ++jj) acc[jj][r] *= sc;
    }

    // P (C layout) -> Ps (A layout staging)
#pragma unroll
    for (int r = 0; r < 4; ++r)
#pragma unroll
      for (int j = 0; j < 4; ++j) Ps[wave][lg * 4 + r][j * 16 + lr] = f2bf(s[j][r]);

    bf16x8 pa0 = *(const bf16x8*)(&Ps[wave][lr][lg * 8]);
    bf16x8 pa1 = *(const bf16x8*)(&Ps[wave][lr][32 + lg * 8]);
#pragma unroll
    for (int jj = 0; jj < 4; ++jj) {
      bf16x8 bv0 = *(const bf16x8*)(&Vs[jj * 16 + lr][lg * 8]);
      bf16x8 bv1 = *(const bf16x8*)(&Vs[jj * 16 + lr][32 + lg * 8]);
      acc[jj] = __builtin_amdgcn_mfma_f32_16x16x32_bf16(pa0, bv0, acc[jj], 0, 0, 0);
      acc[jj] = __builtin_amdgcn_mfma_f32_16x16x32_bf16(pa1, bv1, acc[jj], 0, 0, 0);
    }
  }

  // write O = acc / l
#pragma unroll
  for (int r = 0; r < 4; ++r) {
    float inv = 1.0f / lrow[r];
    int row = b * CT + q0 + wave * 16 + lg * 4 + r;
#pragma unroll
    for (int jj = 0; jj < 4; ++jj)
      out[(size_t)row * CD + h * CDH + jj * 16 + lr] = f2bf(acc[jj][r] * inv);
  }
}

// ---------------- V transpose: qkv V section -> vt [bh][e][t] ----------------
__global__ __launch_bounds__(256) void vtrans_k(const ushort* __restrict__ qkv,
                                                ushort* __restrict__ vt) {
  const int t0 = blockIdx.x * 64;
  const int bh = blockIdx.y;
  const int b = bh / CH, h = bh % CH;
  const int tid = threadIdx.x;
  __shared__ ushort tile[64][72];
#pragma unroll
  for (int p = 0; p < 2; ++p) {
    int i = p * 2048 + tid * 8;
    int tr = i >> 6, c = i & 63;
    *(bf16x8*)(&tile[tr][c]) =
        *(const bf16x8*)(qkv + (size_t)(b * CT + t0 + tr) * 2304 + 2 * CD + h * CDH + c);
  }
  __syncthreads();
#pragma unroll
  for (int p = 0; p < 2; ++p) {
    int i = p * 2048 + tid * 8;
    int er = i >> 6, tc = i & 63;
    ushort tmp[8];
#pragma unroll
    for (int j = 0; j < 8; ++j) tmp[j] = tile[tc + j][er];
    *(bf16x8*)(vt + (size_t)bh * 64 * CT + (size_t)er * CT + t0 + tc) = *(bf16x8*)tmp;
  }
}

// ---------------- mask -> bitmask ----------------
__global__ void maskbits_k(const int* __restrict__ mask, unsigned* __restrict__ mbits) {
  int idx = blockIdx.x * 256 + threadIdx.x;
  if (idx >= CT * 64) return;
  const int* mp = mask + (size_t)(idx >> 6) * CT + (idx & 63) * 32;
  unsigned bits = 0;
#pragma unroll
  for (int j = 0; j < 32; ++j) bits |= (mp[j] != 0 ? 1u : 0u) << j;
  mbits[idx] = bits;
}

// ---------------- layernorm ----------------
__global__ __launch_bounds__(256) void ln_k(const float* __restrict__ X,
                                            ushort* __restrict__ H,
                                            const float* __restrict__ g,
                                            const float* __restrict__ b) {
  const int t = blockIdx.x;
  const int tid = threadIdx.x;
  const float* row = X + (size_t)t * CD;
  float x0 = row[tid], x1 = row[tid + 256], x2 = row[tid + 512];
  float s = wred_sum(x0 + x1 + x2);
  __shared__ float sh[4], sh2[4];
  if ((tid & 63) == 0) sh[tid >> 6] = s;
  __syncthreads();
  float mu = (sh[0] + sh[1] + sh[2] + sh[3]) * (1.0f / 768.0f);
  float d0 = x0 - mu, d1 = x1 - mu, d2 = x2 - mu;
  float vs = wred_sum(d0 * d0 + d1 * d1 + d2 * d2);
  if ((tid & 63) == 0) sh2[tid >> 6] = vs;
  __syncthreads();
  float var = (sh2[0] + sh2[1] + sh2[2] + sh2[3]) * (1.0f / 768.0f);
  float r = 1.0f / sqrtf(var + 1e-5f);
  H[(size_t)t * CD + tid] = f2bf(d0 * r * g[tid] + b[tid]);
  H[(size_t)t * CD + tid + 256] = f2bf(d1 * r * g[tid + 256] + b[tid + 256]);
  H[(size_t)t * CD + tid + 512] = f2bf(d2 * r * g[tid + 512] + b[tid + 512]);
}

// ---------------- conversions / repacks ----------------
__global__ void f32_to_bf16_k(const float* __restrict__ in, ushort* __restrict__ out, int n4) {
  int i = blockIdx.x * 256 + threadIdx.x;
  if (i >= n4) return;
  float4 f = *(const float4*)(in + (size_t)i * 4);
  ushort4 u;
  u.x = f2bf(f.x); u.y = f2bf(f.y); u.z = f2bf(f.z); u.w = f2bf(f.w);
  *(ushort4*)(out + (size_t)i * 4) = u;
}

__global__ void repack_qkvw_k(const float* __restrict__ Wq, const float* __restrict__ Wk,
                              const float* __restrict__ Wv, ushort* __restrict__ dst) {
  int idx = blockIdx.x * 256 + threadIdx.x;
  if (idx >= CL * 2304 * CD) return;
  int l = idx / (2304 * CD);
  int rem = idx % (2304 * CD);
  int c = rem / CD;
  int d = rem % CD;
  int sec = c / CD;
  int within = c % CD;
  int h = within / CDH;
  int e = within % CDH;
  const float* W = (sec == 0) ? Wq : ((sec == 1) ? Wk : Wv);
  float v = W[(((size_t)l * CH + h) * CD + d) * CDH + e];
  dst[idx] = f2bf(v);
}

__global__ void repack_wo_k(const float* __restrict__ Wo, ushort* __restrict__ dst) {
  int idx = blockIdx.x * 256 + threadIdx.x;
  if (idx >= CL * CD * CD) return;
  int l = idx / (CD * CD);
  int rem = idx % (CD * CD);
  int n = rem / CD;
  int k = rem % CD;
  dst[idx] = f2bf(Wo[((size_t)l * CD + k) * CD + n]);
}

__global__ void repack_w1_k(const float* __restrict__ W1, ushort* __restrict__ dst) {
  int idx = blockIdx.x * 256 + threadIdx.x;
  if (idx >= CL * CF * CD) return;
  int l = idx / (CF * CD);
  int rem = idx % (CF * CD);
  int f = rem / CD;
  int d = rem % CD;
  dst[idx] = f2bf(W1[((size_t)l * CD + d) * CF + f]);
}

__global__ void repack_w2_k(const float* __restrict__ W2, ushort* __restrict__ dst) {
  int idx = blockIdx.x * 256 + threadIdx.x;
  if (idx >= CL * CD * CF) return;
  int l = idx / (CD * CF);
  int rem = idx % (CD * CF);
  int d = rem / CF;
  int f = rem % CF;
  dst[idx] = f2bf(W2[((size_t)l * CF + f) * CD + d]);
}

__global__ void repack_bqkv_k(const float* __restrict__ bq, const float* __restrict__ bk,
                              const float* __restrict__ bv, float* __restrict__ dst) {
  int idx = blockIdx.x * 256 + threadIdx.x;
  if (idx >= CL * 2304) return;
  int l = idx / 2304;
  int c = idx % 2304;
  int sec = c / CD;
  int within = c % CD;
  int h = within / CDH;
  int e = within % CDH;
  const float* B = (sec == 0) ? bq : ((sec == 1) ? bk : bv);
  dst[idx] = B[((size_t)l * CH + h) * CDH + e];
}

extern "C" void kernel_launch(void* const* d_in, const int* in_sizes, int n_in,
                              void* d_out, int out_size, void* d_ws, size_t ws_size,
                              hipStream_t stream) {
  (void)in_sizes; (void)n_in; (void)out_size; (void)ws_size;
  const float* X = (const float*)d_in[0];
  const int* MSK = (const int*)d_in[1];
  const float* Wq = (const float*)d_in[2];
  const float* bq = (const float*)d_in[3];
  const float* Wk = (const float*)d_in[4];
  const float* bk = (const float*)d_in[5];
  const float* Wv = (const float*)d_in[6];
  const float* bv = (const float*)d_in[7];
  const float* Wo = (const float*)d_in[8];
  const float* bo = (const float*)d_in[9];
  const float* lng = (const float*)d_in[10];
  const float* lnb = (const float*)d_in[11];
  const float* W1 = (const float*)d_in[12];
  const float* b1 = (const float*)d_in[13];
  const float* W2 = (const float*)d_in[14];
  const float* b2 = (const float*)d_in[15];

  char* base = (char*)d_ws;
  size_t off = 0;
  auto alloc = [&](size_t bytes) {
    char* p = base + off;
    off = (off + bytes + 255) & ~(size_t)255;
    return p;
  };
  ushort* wqkv_t = (ushort*)alloc((size_t)CL * 2304 * CD * 2);
  ushort* wo_t = (ushort*)alloc((size_t)CL * CD * CD * 2);
  ushort* w1_t = (ushort*)alloc((size_t)CL * CF * CD * 2);
  ushort* w2_t = (ushort*)alloc((size_t)CL * CD * CF * 2);
  float* bqkv = (float*)alloc((size_t)CL * 2304 * 4);
  ushort* xb = (ushort*)alloc((size_t)CB * CT * CD * 2);
  ushort* qkv = (ushort*)alloc((size_t)CB * CT * 2304 * 2);
  ushort* vt = (ushort*)alloc((size_t)CB * CH * CDH * CT * 2);
  unsigned* mbits = (unsigned*)alloc((size_t)CT * 64 * 4);
  ushort* attno = (ushort*)alloc((size_t)CB * CT * CD * 2);
  float* xattn = (float*)alloc((size_t)CB * CT * CD * 4);
  float* xf = (float*)alloc((size_t)CB * CT * CD * 4);
  ushort* hln = (ushort*)alloc((size_t)CB * CT * CD * 2);
  ushort* gbuf = (ushort*)alloc((size_t)CB * CT * CF * 2);

  const int BT_ = CB * CT;  // 4096 rows

  // one-time preprocessing
  {
    int n = CL * 2304 * CD;
    repack_qkvw_k<<<(n + 255) / 256, 256, 0, stream>>>(Wq, Wk, Wv, wqkv_t);
  }
  {
    int n = CL * CD * CD;
    repack_wo_k<<<(n + 255) / 256, 256, 0, stream>>>(Wo, wo_t);
  }
  {
    int n = CL * CF * CD;
    repack_w1_k<<<(n + 255) / 256, 256, 0, stream>>>(W1, w1_t);
    repack_w2_k<<<(n + 255) / 256, 256, 0, stream>>>(W2, w2_t);
  }
  {
    int n = CL * 2304;
    repack_bqkv_k<<<(n + 255) / 256, 256, 0, stream>>>(bq, bk, bv, bqkv);
  }
  maskbits_k<<<(CT * 64 + 255) / 256, 256, 0, stream>>>(MSK, mbits);

  // layer-0 input -> bf16 (layer 1 gets it fused from FFN2's epilogue)
  {
    int n4 = BT_ * CD / 4;
    f32_to_bf16_k<<<(n4 + 255) / 256, 256, 0, stream>>>(X, xb, n4);
  }

  for (int l = 0; l < CL; ++l) {
    const float* xcur = (l == 0) ? X : xf;
    // QKV projection: (4096x768) @ (768x2304) + bias -> qkv bf16
    gemm_k<EPI_BIAS_BF16><<<dim3(2304 / 128, BT_ / 128), 256, 0, stream>>>(
        xb, CD, wqkv_t + (size_t)l * 2304 * CD, CD, qkv, 2304, CD,
        bqkv + (size_t)l * 2304, nullptr, nullptr);
    // V transpose + fused flash attention
    vtrans_k<<<dim3(CT / 64, CB * CH), 256, 0, stream>>>(qkv, vt);
    flash_k<<<dim3(CT / 64, CB * CH), 256, 0, stream>>>(qkv, vt, mbits, attno);
    // output projection + bias + residual -> xattn (fp32)
    gemm_k<EPI_BIAS_RES_F32><<<dim3(CD / 128, BT_ / 128), 256, 0, stream>>>(
        attno, CD, wo_t + (size_t)l * CD * CD, CD, xattn, CD, CD,
        bo + (size_t)l * CD, xcur, nullptr);
    // layernorm -> hln bf16
    ln_k<<<BT_, 256, 0, stream>>>(xattn, hln, lng + (size_t)l * CD, lnb + (size_t)l * CD);
    // FFN1 + bias + gelu -> gbuf bf16
    gemm_k<EPI_BIAS_GELU_BF16><<<dim3(CF / 128, BT_ / 128), 256, 0, stream>>>(
        hln, CD, w1_t + (size_t)l * CF * CD, CD, gbuf, CF, CD,
        b1 + (size_t)l * CF, nullptr, nullptr);
    // FFN2 + bias + residual -> xf (+ fused bf16 for next layer's GEMM-A) or d_out
    if (l == CL - 1) {
      gemm_k<EPI_BIAS_RES_F32><<<dim3(CD / 128, BT_ / 128), 256, 0, stream>>>(
          gbuf, CF, w2_t + (size_t)l * CD * CF, CF, (float*)d_out, CD, CF,
          b2 + (size_t)l * CD, xattn, nullptr);
    } else {
      gemm_k<EPI_BIAS_RES_F32_BF16><<<dim3(CD / 128, BT_ / 128), 256, 0, stream>>>(
          gbuf, CF, w2_t + (size_t)l * CD * CF, CF, xf, CD, CF,
          b2 + (size_t)l * CD, xattn, xb);
    }
  }
}

// Round 4
// 529.994 us; speedup vs baseline: 12.0491x; 1.1992x over previous
//
#include <hip/hip_runtime.h>
#include <math.h>

// Problem constants
#define CL 2
#define CH 12
#define CD 768
#define CDH 64
#define CF 3072
#define CB 2
#define CT 2048

typedef __bf16 bf16x8 __attribute__((ext_vector_type(8)));
typedef float f32x4 __attribute__((ext_vector_type(4)));
typedef short s16x4 __attribute__((ext_vector_type(4)));
typedef ushort u16x4 __attribute__((ext_vector_type(4)));

__device__ __forceinline__ ushort f2bf(float f) {
  return __builtin_bit_cast(ushort, (__bf16)f);
}

__device__ __forceinline__ float fexp2(float x) {
  float r;
  asm volatile("v_exp_f32 %0, %1" : "=v"(r) : "v"(x));
  return r;
}

__device__ __forceinline__ float wred_sum(float v) {
#pragma unroll
  for (int o = 32; o > 0; o >>= 1) v += __shfl_xor(v, o);
  return v;
}

// async global->LDS, 16B per lane. LDS dest = wave-uniform base + lane*16.
__device__ __forceinline__ void gload16(const ushort* g, ushort* l) {
  __builtin_amdgcn_global_load_lds(
      (const __attribute__((address_space(1))) unsigned int*)g,
      (__attribute__((address_space(3))) unsigned int*)l, 16, 0, 0);
}

// ---------------- GEMM (m97 structure + dbuf pipeline + XCD swizzle) ------
// C(MxN) = A(MxK) @ B, A bf16 row-major (lda), B stored (N x K) row-major (ldb).
// REQUIRES: M % 128 == 0, N % 128 == 0, K % 64 == 0, grid % 8 == 0.
enum { EPI_BF16 = 1, EPI_BIAS_BF16 = 2, EPI_BIAS_GELU_BF16 = 3, EPI_BIAS_RES_F32 = 4, EPI_BIAS_RES_F32_BF16 = 5 };

template <int EPI>
__global__ __launch_bounds__(256) void gemm_k(
    const ushort* __restrict__ A, int lda,
    const ushort* __restrict__ B, int ldb,
    void* __restrict__ Cv, int ldc,
    int K,
    const float* __restrict__ bias,
    const float* __restrict__ res,
    ushort* __restrict__ C2) {
  __shared__ ushort As[2][128 * 32];
  __shared__ ushort Bs[2][128 * 32];
  const int tid = threadIdx.x;
  const int lane = tid & 63;
  const int wave = tid >> 6;
  const int wm = (wave >> 1) * 64;
  const int wn = (wave & 1) * 64;

  // bijective XCD swizzle (grid multiple of 8): contiguous chunk per XCD
  const int gx = gridDim.x;
  const int nwg = gx * gridDim.y;
  int wgid = blockIdx.y * gx + blockIdx.x;
  const int cpx = nwg >> 3;
  wgid = (wgid & 7) * cpx + (wgid >> 3);
  const int m0 = (wgid / gx) * 128;
  const int n0 = (wgid % gx) * 128;

  const int lr = lane & 15;
  const int lg = lane >> 4;
  f32x4 acc[4][4] = {};

  // staging: lane covers row p*64 + tid/4, cols (tid&3)*8
  const ushort* pa = A + (size_t)(m0 + (tid >> 2)) * lda + (tid & 3) * 8;
  const ushort* pb = B + (size_t)(n0 + (tid >> 2)) * ldb + (tid & 3) * 8;

  auto stage = [&](int buf, int k0) {
#pragma unroll
    for (int p = 0; p < 2; ++p) {
      gload16(pa + (size_t)p * 64 * lda + k0, &As[buf][wave * 512 + p * 2048]);
      gload16(pb + (size_t)p * 64 * ldb + k0, &Bs[buf][wave * 512 + p * 2048]);
    }
  };

  const int nt = K >> 5;
  stage(0, 0);
  for (int kt = 0; kt < nt; ++kt) {
    const int cur = kt & 1;
    if (kt + 1 < nt) {
      stage(cur ^ 1, (kt + 1) << 5);
      asm volatile("s_waitcnt vmcnt(4)" ::: "memory");
    } else {
      asm volatile("s_waitcnt vmcnt(0)" ::: "memory");
    }
    __builtin_amdgcn_s_barrier();
    __builtin_amdgcn_sched_barrier(0);

    bf16x8 af[4], bfr[4];
#pragma unroll
    for (int f = 0; f < 4; ++f) af[f] = *(const bf16x8*)(&As[cur][(wm + f * 16 + lr) * 32 + lg * 8]);
#pragma unroll
    for (int f = 0; f < 4; ++f) bfr[f] = *(const bf16x8*)(&Bs[cur][(wn + f * 16 + lr) * 32 + lg * 8]);
#pragma unroll
    for (int i = 0; i < 4; ++i)
#pragma unroll
      for (int j = 0; j < 4; ++j)
        acc[i][j] = __builtin_amdgcn_mfma_f32_16x16x32_bf16(af[i], bfr[j], acc[i][j], 0, 0, 0);

    __builtin_amdgcn_sched_barrier(0);
    __builtin_amdgcn_s_barrier();
  }

  // epilogue: lane holds D[row=(lane>>4)*4+r][col=lane&15] per frag
  const int cr0 = lg * 4;
#pragma unroll
  for (int i = 0; i < 4; ++i) {
#pragma unroll
    for (int j = 0; j < 4; ++j) {
      int col = n0 + wn + j * 16 + lr;
#pragma unroll
      for (int r = 0; r < 4; ++r) {
        int row = m0 + wm + i * 16 + cr0 + r;
        float val = acc[i][j][r];
        size_t offc = (size_t)row * ldc + col;
        if constexpr (EPI == EPI_BF16) {
          ((ushort*)Cv)[offc] = f2bf(val);
        } else if constexpr (EPI == EPI_BIAS_BF16) {
          ((ushort*)Cv)[offc] = f2bf(val + bias[col]);
        } else if constexpr (EPI == EPI_BIAS_GELU_BF16) {
          float x = val + bias[col];
          float gel = 0.5f * x * (1.0f + erff(x * 0.70710678118654752f));
          ((ushort*)Cv)[offc] = f2bf(gel);
        } else if constexpr (EPI == EPI_BIAS_RES_F32) {
          ((float*)Cv)[offc] = val + bias[col] + res[offc];
        } else {
          float o = val + bias[col] + res[offc];
          ((float*)Cv)[offc] = o;
          C2[offc] = f2bf(o);
        }
      }
    }
  }
}

// ---------------- flash attention (swapped QK^T, in-register softmax) -----
// grid: (CT/64, CB*CH). block 256 = 4 waves; each wave owns 16 q rows (q=lr).
// Lane (lg,lr) holds S^T[kv=j*16+lg*4+r][q=lr] -> P feeds 16x16x16 PV mfma
// as B-frag directly; A-frag = V^T from LDS. O^T accumulates in C-layout.
__global__ __launch_bounds__(256) void flash_k(const ushort* __restrict__ qkv,
                                               const ushort* __restrict__ vt,
                                               const unsigned* __restrict__ mbits,
                                               ushort* __restrict__ out) {
  const int q0 = blockIdx.x * 64;
  const int bh = blockIdx.y;
  const int b = bh / CH, h = bh % CH;
  const int tid = threadIdx.x;
  const int lane = tid & 63;
  const int wave = tid >> 6;
  const int lr = lane & 15;
  const int lg = lane >> 4;

  __shared__ ushort Ks[64][72];   // [kv][d]
  __shared__ ushort Vt[64][72];   // [e][kv]

  const float SCL2 = 0.125f * 1.44269504088896f;  // (1/sqrt(64)) * log2(e)

  const int qg = q0 + wave * 16 + lr;  // this lane's q row
  const ushort* qrow = qkv + ((size_t)(b * CT) + qg) * 2304 + h * CDH;
  bf16x8 aq0 = *(const bf16x8*)(qrow);
  bf16x8 aq1 = *(const bf16x8*)(qrow + 32);
  // shift to fragment position (k = lg*8)
  aq0 = *(const bf16x8*)(qrow + lg * 8);
  aq1 = *(const bf16x8*)(qrow + 32 + lg * 8);

  f32x4 acc[4] = {};              // O^T frags: acc[jj][r] = O^T[jj*16+lg*4+r][q=lr]
  float m_run = -1e30f, l_run = 0.f;

  const ushort* kbase = qkv + (size_t)(b * CT) * 2304 + CD + h * CDH;
  const ushort* vbase = vt + (size_t)bh * 64 * CT;

  for (int kv0 = 0; kv0 < CT; kv0 += 64) {
    __syncthreads();
#pragma unroll
    for (int p = 0; p < 2; ++p) {
      int i = p * 2048 + tid * 8;
      int r = i >> 6, c = i & 63;
      *(bf16x8*)(&Ks[r][c]) = *(const bf16x8*)(kbase + (size_t)(kv0 + r) * 2304 + c);
      *(bf16x8*)(&Vt[r][c]) = *(const bf16x8*)(vbase + (size_t)r * CT + kv0 + c);
    }
    __syncthreads();

    // S^T = K Q^T (4 tiles of 16 kv x 16 q)
    f32x4 st[4];
#pragma unroll
    for (int j = 0; j < 4; ++j) {
      bf16x8 kf0 = *(const bf16x8*)(&Ks[j * 16 + lr][lg * 8]);
      bf16x8 kf1 = *(const bf16x8*)(&Ks[j * 16 + lr][32 + lg * 8]);
      f32x4 t = {};
      t = __builtin_amdgcn_mfma_f32_16x16x32_bf16(kf0, aq0, t, 0, 0, 0);
      t = __builtin_amdgcn_mfma_f32_16x16x32_bf16(kf1, aq1, t, 0, 0, 0);
      st[j] = t;
    }

    // scale + mask (in log2 domain), in-lane max over 16 kv values
    unsigned w0 = mbits[(size_t)qg * 64 + (kv0 >> 5)];
    unsigned w1 = mbits[(size_t)qg * 64 + (kv0 >> 5) + 1];
    float tmax = -INFINITY;
#pragma unroll
    for (int j = 0; j < 4; ++j) {
      unsigned w = (j < 2) ? w0 : w1;
#pragma unroll
      for (int r = 0; r < 4; ++r) {
        float x = st[j][r] * SCL2;
        int bit = (j * 16 + lg * 4 + r) & 31;
        if (((w >> bit) & 1u) == 0u) x = -INFINITY;
        st[j][r] = x;
        tmax = fmaxf(tmax, x);
      }
    }
    // cross-lane: q-row mates are lanes lr, lr+16, lr+32, lr+48
    tmax = fmaxf(tmax, __shfl_xor(tmax, 16));
    tmax = fmaxf(tmax, __shfl_xor(tmax, 32));

    float mnew = fmaxf(m_run, tmax);
    float sc = fexp2(m_run - mnew);
    m_run = mnew;

    float tsum = 0.f;
    s16x4 pf[4];
#pragma unroll
    for (int j = 0; j < 4; ++j) {
      s16x4 pv;
#pragma unroll
      for (int r = 0; r < 4; ++r) {
        float p = fexp2(st[j][r] - mnew);
        tsum += p;
        pv[r] = (short)f2bf(p);
      }
      pf[j] = pv;
    }
    tsum += __shfl_xor(tsum, 16);
    tsum += __shfl_xor(tsum, 32);
    l_run = l_run * sc + tsum;

#pragma unroll
    for (int jj = 0; jj < 4; ++jj) {
      acc[jj][0] *= sc; acc[jj][1] *= sc; acc[jj][2] *= sc; acc[jj][3] *= sc;
    }

    // PV: O^T[e][q] += V^T[e][kv] * P^T[kv][q], 16x16x16 mfma, K=16 per tile j
#pragma unroll
    for (int jj = 0; jj < 4; ++jj) {
#pragma unroll
      for (int j = 0; j < 4; ++j) {
        s16x4 vf = *(const s16x4*)(&Vt[jj * 16 + lr][j * 16 + lg * 4]);
        acc[jj] = __builtin_amdgcn_mfma_f32_16x16x16bf16_1k(vf, pf[j], acc[jj], 0, 0, 0);
      }
    }
  }

  // write O: lane holds O^T[e=jj*16+lg*4+r][q=lr] -> out[qg][h*64+e]
  float inv = 1.0f / l_run;
  const int orow = b * CT + qg;
#pragma unroll
  for (int jj = 0; jj < 4; ++jj) {
    u16x4 o;
#pragma unroll
    for (int r = 0; r < 4; ++r) o[r] = f2bf(acc[jj][r] * inv);
    *(u16x4*)(out + (size_t)orow * CD + h * CDH + jj * 16 + lg * 4) = o;
  }
}

// ---------------- V transpose: qkv V section -> vt [bh][e][t] ----------------
__global__ __launch_bounds__(256) void vtrans_k(const ushort* __restrict__ qkv,
                                                ushort* __restrict__ vt) {
  const int t0 = blockIdx.x * 64;
  const int bh = blockIdx.y;
  const int b = bh / CH, h = bh % CH;
  const int tid = threadIdx.x;
  __shared__ ushort tile[64][72];
#pragma unroll
  for (int p = 0; p < 2; ++p) {
    int i = p * 2048 + tid * 8;
    int tr = i >> 6, c = i & 63;
    *(bf16x8*)(&tile[tr][c]) =
        *(const bf16x8*)(qkv + (size_t)(b * CT + t0 + tr) * 2304 + 2 * CD + h * CDH + c);
  }
  __syncthreads();
#pragma unroll
  for (int p = 0; p < 2; ++p) {
    int i = p * 2048 + tid * 8;
    int er = i >> 6, tc = i & 63;
    ushort tmp[8];
#pragma unroll
    for (int j = 0; j < 8; ++j) tmp[j] = tile[tc + j][er];
    *(bf16x8*)(vt + (size_t)bh * 64 * CT + (size_t)er * CT + t0 + tc) = *(bf16x8*)tmp;
  }
}

// ---------------- mask -> bitmask ----------------
__global__ void maskbits_k(const int* __restrict__ mask, unsigned* __restrict__ mbits) {
  int idx = blockIdx.x * 256 + threadIdx.x;
  if (idx >= CT * 64) return;
  const int* mp = mask + (size_t)(idx >> 6) * CT + (idx & 63) * 32;
  unsigned bits = 0;
#pragma unroll
  for (int j = 0; j < 32; ++j) bits |= (mp[j] != 0 ? 1u : 0u) << j;
  mbits[idx] = bits;
}

// ---------------- layernorm ----------------
__global__ __launch_bounds__(256) void ln_k(const float* __restrict__ X,
                                            ushort* __restrict__ H,
                                            const float* __restrict__ g,
                                            const float* __restrict__ b) {
  const int t = blockIdx.x;
  const int tid = threadIdx.x;
  const float* row = X + (size_t)t * CD;
  float x0 = row[tid], x1 = row[tid + 256], x2 = row[tid + 512];
  float s = wred_sum(x0 + x1 + x2);
  __shared__ float sh[4], sh2[4];
  if ((tid & 63) == 0) sh[tid >> 6] = s;
  __syncthreads();
  float mu = (sh[0] + sh[1] + sh[2] + sh[3]) * (1.0f / 768.0f);
  float d0 = x0 - mu, d1 = x1 - mu, d2 = x2 - mu;
  float vs = wred_sum(d0 * d0 + d1 * d1 + d2 * d2);
  if ((tid & 63) == 0) sh2[tid >> 6] = vs;
  __syncthreads();
  float var = (sh2[0] + sh2[1] + sh2[2] + sh2[3]) * (1.0f / 768.0f);
  float r = 1.0f / sqrtf(var + 1e-5f);
  H[(size_t)t * CD + tid] = f2bf(d0 * r * g[tid] + b[tid]);
  H[(size_t)t * CD + tid + 256] = f2bf(d1 * r * g[tid + 256] + b[tid + 256]);
  H[(size_t)t * CD + tid + 512] = f2bf(d2 * r * g[tid + 512] + b[tid + 512]);
}

// ---------------- conversions / repacks ----------------
__global__ void f32_to_bf16_k(const float* __restrict__ in, ushort* __restrict__ out, int n4) {
  int i = blockIdx.x * 256 + threadIdx.x;
  if (i >= n4) return;
  float4 f = *(const float4*)(in + (size_t)i * 4);
  ushort4 u;
  u.x = f2bf(f.x); u.y = f2bf(f.y); u.z = f2bf(f.z); u.w = f2bf(f.w);
  *(ushort4*)(out + (size_t)i * 4) = u;
}

__global__ void repack_qkvw_k(const float* __restrict__ Wq, const float* __restrict__ Wk,
                              const float* __restrict__ Wv, ushort* __restrict__ dst) {
  int idx = blockIdx.x * 256 + threadIdx.x;
  if (idx >= CL * 2304 * CD) return;
  int l = idx / (2304 * CD);
  int rem = idx % (2304 * CD);
  int c = rem / CD;
  int d = rem % CD;
  int sec = c / CD;
  int within = c % CD;
  int h = within / CDH;
  int e = within % CDH;
  const float* W = (sec == 0) ? Wq : ((sec == 1) ? Wk : Wv);
  float v = W[(((size_t)l * CH + h) * CD + d) * CDH + e];
  dst[idx] = f2bf(v);
}

__global__ void repack_wo_k(const float* __restrict__ Wo, ushort* __restrict__ dst) {
  int idx = blockIdx.x * 256 + threadIdx.x;
  if (idx >= CL * CD * CD) return;
  int l = idx / (CD * CD);
  int rem = idx % (CD * CD);
  int n = rem / CD;
  int k = rem % CD;
  dst[idx] = f2bf(Wo[((size_t)l * CD + k) * CD + n]);
}

__global__ void repack_w1_k(const float* __restrict__ W1, ushort* __restrict__ dst) {
  int idx = blockIdx.x * 256 + threadIdx.x;
  if (idx >= CL * CF * CD) return;
  int l = idx / (CF * CD);
  int rem = idx % (CF * CD);
  int f = rem / CD;
  int d = rem % CD;
  dst[idx] = f2bf(W1[((size_t)l * CD + d) * CF + f]);
}

__global__ void repack_w2_k(const float* __restrict__ W2, ushort* __restrict__ dst) {
  int idx = blockIdx.x * 256 + threadIdx.x;
  if (idx >= CL * CD * CF) return;
  int l = idx / (CD * CF);
  int rem = idx % (CD * CF);
  int d = rem / CF;
  int f = rem % CF;
  dst[idx] = f2bf(W2[((size_t)l * CF + f) * CD + d]);
}

__global__ void repack_bqkv_k(const float* __restrict__ bq, const float* __restrict__ bk,
                              const float* __restrict__ bv, float* __restrict__ dst) {
  int idx = blockIdx.x * 256 + threadIdx.x;
  if (idx >= CL * 2304) return;
  int l = idx / 2304;
  int c = idx % 2304;
  int sec = c / CD;
  int within = c % CD;
  int h = within / CDH;
  int e = within % CDH;
  const float* B = (sec == 0) ? bq : ((sec == 1) ? bk : bv);
  dst[idx] = B[((size_t)l * CH + h) * CDH + e];
}

extern "C" void kernel_launch(void* const* d_in, const int* in_sizes, int n_in,
                              void* d_out, int out_size, void* d_ws, size_t ws_size,
                              hipStream_t stream) {
  (void)in_sizes; (void)n_in; (void)out_size; (void)ws_size;
  const float* X = (const float*)d_in[0];
  const int* MSK = (const int*)d_in[1];
  const float* Wq = (const float*)d_in[2];
  const float* bq = (const float*)d_in[3];
  const float* Wk = (const float*)d_in[4];
  const float* bk = (const float*)d_in[5];
  const float* Wv = (const float*)d_in[6];
  const float* bv = (const float*)d_in[7];
  const float* Wo = (const float*)d_in[8];
  const float* bo = (const float*)d_in[9];
  const float* lng = (const float*)d_in[10];
  const float* lnb = (const float*)d_in[11];
  const float* W1 = (const float*)d_in[12];
  const float* b1 = (const float*)d_in[13];
  const float* W2 = (const float*)d_in[14];
  const float* b2 = (const float*)d_in[15];

  char* base = (char*)d_ws;
  size_t off = 0;
  auto alloc = [&](size_t bytes) {
    char* p = base + off;
    off = (off + bytes + 255) & ~(size_t)255;
    return p;
  };
  ushort* wqkv_t = (ushort*)alloc((size_t)CL * 2304 * CD * 2);
  ushort* wo_t = (ushort*)alloc((size_t)CL * CD * CD * 2);
  ushort* w1_t = (ushort*)alloc((size_t)CL * CF * CD * 2);
  ushort* w2_t = (ushort*)alloc((size_t)CL * CD * CF * 2);
  float* bqkv = (float*)alloc((size_t)CL * 2304 * 4);
  ushort* xb = (ushort*)alloc((size_t)CB * CT * CD * 2);
  ushort* qkv = (ushort*)alloc((size_t)CB * CT * 2304 * 2);
  ushort* vt = (ushort*)alloc((size_t)CB * CH * CDH * CT * 2);
  unsigned* mbits = (unsigned*)alloc((size_t)CT * 64 * 4);
  ushort* attno = (ushort*)alloc((size_t)CB * CT * CD * 2);
  float* xattn = (float*)alloc((size_t)CB * CT * CD * 4);
  float* xf = (float*)alloc((size_t)CB * CT * CD * 4);
  ushort* hln = (ushort*)alloc((size_t)CB * CT * CD * 2);
  ushort* gbuf = (ushort*)alloc((size_t)CB * CT * CF * 2);

  const int BT_ = CB * CT;  // 4096 rows

  // one-time preprocessing
  {
    int n = CL * 2304 * CD;
    repack_qkvw_k<<<(n + 255) / 256, 256, 0, stream>>>(Wq, Wk, Wv, wqkv_t);
  }
  {
    int n = CL * CD * CD;
    repack_wo_k<<<(n + 255) / 256, 256, 0, stream>>>(Wo, wo_t);
  }
  {
    int n = CL * CF * CD;
    repack_w1_k<<<(n + 255) / 256, 256, 0, stream>>>(W1, w1_t);
    repack_w2_k<<<(n + 255) / 256, 256, 0, stream>>>(W2, w2_t);
  }
  {
    int n = CL * 2304;
    repack_bqkv_k<<<(n + 255) / 256, 256, 0, stream>>>(bq, bk, bv, bqkv);
  }
  maskbits_k<<<(CT * 64 + 255) / 256, 256, 0, stream>>>(MSK, mbits);

  // layer-0 input -> bf16 (layer 1 gets it fused from FFN2's epilogue)
  {
    int n4 = BT_ * CD / 4;
    f32_to_bf16_k<<<(n4 + 255) / 256, 256, 0, stream>>>(X, xb, n4);
  }

  for (int l = 0; l < CL; ++l) {
    const float* xcur = (l == 0) ? X : xf;
    // QKV projection: (4096x768) @ (768x2304) + bias -> qkv bf16
    gemm_k<EPI_BIAS_BF16><<<dim3(2304 / 128, BT_ / 128), 256, 0, stream>>>(
        xb, CD, wqkv_t + (size_t)l * 2304 * CD, CD, qkv, 2304, CD,
        bqkv + (size_t)l * 2304, nullptr, nullptr);
    // V transpose + fused flash attention
    vtrans_k<<<dim3(CT / 64, CB * CH), 256, 0, stream>>>(qkv, vt);
    flash_k<<<dim3(CT / 64, CB * CH), 256, 0, stream>>>(qkv, vt, mbits, attno);
    // output projection + bias + residual -> xattn (fp32)
    gemm_k<EPI_BIAS_RES_F32><<<dim3(CD / 128, BT_ / 128), 256, 0, stream>>>(
        attno, CD, wo_t + (size_t)l * CD * CD, CD, xattn, CD, CD,
        bo + (size_t)l * CD, xcur, nullptr);
    // layernorm -> hln bf16
    ln_k<<<BT_, 256, 0, stream>>>(xattn, hln, lng + (size_t)l * CD, lnb + (size_t)l * CD);
    // FFN1 + bias + gelu -> gbuf bf16
    gemm_k<EPI_BIAS_GELU_BF16><<<dim3(CF / 128, BT_ / 128), 256, 0, stream>>>(
        hln, CD, w1_t + (size_t)l * CF * CD, CD, gbuf, CF, CD,
        b1 + (size_t)l * CF, nullptr, nullptr);
    // FFN2 + bias + residual -> xf (+ fused bf16 for next layer's GEMM-A) or d_out
    if (l == CL - 1) {
      gemm_k<EPI_BIAS_RES_F32><<<dim3(CD / 128, BT_ / 128), 256, 0, stream>>>(
          gbuf, CF, w2_t + (size_t)l * CD * CF, CF, (float*)d_out, CD, CF,
          b2 + (size_t)l * CD, xattn, nullptr);
    } else {
      gemm_k<EPI_BIAS_RES_F32_BF16><<<dim3(CD / 128, BT_ / 128), 256, 0, stream>>>(
          gbuf, CF, w2_t + (size_t)l * CD * CF, CF, xf, CD, CF,
          b2 + (size_t)l * CD, xattn, xb);
    }
  }
}

// Round 5
// 440.272 us; speedup vs baseline: 14.5046x; 1.2038x over previous
//
#include <hip/hip_runtime.h>
#include <math.h>

// Problem constants
#define CL 2
#define CH 12
#define CD 768
#define CDH 64
#define CF 3072
#define CB 2
#define CT 2048
#define CBTCD ((size_t)CB * CT * CD)

typedef __bf16 bf16x8 __attribute__((ext_vector_type(8)));
typedef float f32x4 __attribute__((ext_vector_type(4)));
typedef short s16x4 __attribute__((ext_vector_type(4)));
typedef ushort u16x4 __attribute__((ext_vector_type(4)));

// 0.125 * log2(e): folded into Wq/bq so QK^T lands in exp2 domain
#define QSCALE 0.18033688011112042f

__device__ __forceinline__ ushort f2bf(float f) {
  return __builtin_bit_cast(ushort, (__bf16)f);
}

__device__ __forceinline__ float fexp2(float x) {
  float r;
  asm volatile("v_exp_f32 %0, %1" : "=v"(r) : "v"(x));
  return r;
}

__device__ __forceinline__ float wred_sum(float v) {
#pragma unroll
  for (int o = 32; o > 0; o >>= 1) v += __shfl_xor(v, o);
  return v;
}

// async global->LDS, 16B per lane. LDS dest = wave-uniform base + lane*16.
__device__ __forceinline__ void gload16(const ushort* g, ushort* l) {
  __builtin_amdgcn_global_load_lds(
      (const __attribute__((address_space(1))) unsigned int*)g,
      (__attribute__((address_space(3))) unsigned int*)l, 16, 0, 0);
}

// ---------------- GEMM (m97 structure + dbuf pipeline + XCD swizzle) ------
// C(MxN) = A(MxK) @ B, A bf16 row-major (lda), B stored (N x K) row-major (ldb).
// REQUIRES: M % 128 == 0, N % 128 == 0, K % 64 == 0, (gridX*gridY) % 8 == 0.
// blockIdx.z = K-split index (K = per-split K); EPI_PART_F32 writes f32
// partials at part[z * CBTCD + row*ldc + col].
enum { EPI_BF16 = 1, EPI_BIAS_BF16 = 2, EPI_BIAS_GELU_BF16 = 3, EPI_BIAS_RES_F32 = 4, EPI_BIAS_RES_F32_BF16 = 5, EPI_PART_F32 = 6 };

template <int EPI>
__global__ __launch_bounds__(256) void gemm_k(
    const ushort* __restrict__ A, int lda,
    const ushort* __restrict__ B, int ldb,
    void* __restrict__ Cv, int ldc,
    int K,
    const float* __restrict__ bias,
    const float* __restrict__ res,
    ushort* __restrict__ C2) {
  __shared__ ushort As[2][128 * 32];
  __shared__ ushort Bs[2][128 * 32];
  const int tid = threadIdx.x;
  const int lane = tid & 63;
  const int wave = tid >> 6;
  const int wm = (wave >> 1) * 64;
  const int wn = (wave & 1) * 64;

  // bijective XCD swizzle (gridX*gridY multiple of 8)
  const int gx = gridDim.x;
  const int nwg = gx * gridDim.y;
  int wgid = blockIdx.y * gx + blockIdx.x;
  const int cpx = nwg >> 3;
  wgid = (wgid & 7) * cpx + (wgid >> 3);
  const int m0 = (wgid / gx) * 128;
  const int n0 = (wgid % gx) * 128;

  const int lr = lane & 15;
  const int lg = lane >> 4;
  f32x4 acc[4][4] = {};

  const int kz = blockIdx.z * K;  // K-split offset (0 for non-split launches)
  const ushort* pa = A + (size_t)(m0 + (tid >> 2)) * lda + (tid & 3) * 8 + kz;
  const ushort* pb = B + (size_t)(n0 + (tid >> 2)) * ldb + (tid & 3) * 8 + kz;

  auto stage = [&](int buf, int k0) {
#pragma unroll
    for (int p = 0; p < 2; ++p) {
      gload16(pa + (size_t)p * 64 * lda + k0, &As[buf][wave * 512 + p * 2048]);
      gload16(pb + (size_t)p * 64 * ldb + k0, &Bs[buf][wave * 512 + p * 2048]);
    }
  };

  const int nt = K >> 5;
  stage(0, 0);
  for (int kt = 0; kt < nt; ++kt) {
    const int cur = kt & 1;
    if (kt + 1 < nt) {
      stage(cur ^ 1, (kt + 1) << 5);
      asm volatile("s_waitcnt vmcnt(4)" ::: "memory");
    } else {
      asm volatile("s_waitcnt vmcnt(0)" ::: "memory");
    }
    __builtin_amdgcn_s_barrier();
    __builtin_amdgcn_sched_barrier(0);

    bf16x8 af[4], bfr[4];
#pragma unroll
    for (int f = 0; f < 4; ++f) af[f] = *(const bf16x8*)(&As[cur][(wm + f * 16 + lr) * 32 + lg * 8]);
#pragma unroll
    for (int f = 0; f < 4; ++f) bfr[f] = *(const bf16x8*)(&Bs[cur][(wn + f * 16 + lr) * 32 + lg * 8]);
#pragma unroll
    for (int i = 0; i < 4; ++i)
#pragma unroll
      for (int j = 0; j < 4; ++j)
        acc[i][j] = __builtin_amdgcn_mfma_f32_16x16x32_bf16(af[i], bfr[j], acc[i][j], 0, 0, 0);

    __builtin_amdgcn_sched_barrier(0);
    __builtin_amdgcn_s_barrier();
  }

  // epilogue: lane holds D[row=(lane>>4)*4+r][col=lane&15] per frag
  const int cr0 = lg * 4;
#pragma unroll
  for (int i = 0; i < 4; ++i) {
#pragma unroll
    for (int j = 0; j < 4; ++j) {
      int col = n0 + wn + j * 16 + lr;
#pragma unroll
      for (int r = 0; r < 4; ++r) {
        int row = m0 + wm + i * 16 + cr0 + r;
        float val = acc[i][j][r];
        size_t offc = (size_t)row * ldc + col;
        if constexpr (EPI == EPI_BF16) {
          ((ushort*)Cv)[offc] = f2bf(val);
        } else if constexpr (EPI == EPI_BIAS_BF16) {
          ((ushort*)Cv)[offc] = f2bf(val + bias[col]);
        } else if constexpr (EPI == EPI_BIAS_GELU_BF16) {
          float x = val + bias[col];
          float gel = 0.5f * x * (1.0f + erff(x * 0.70710678118654752f));
          ((ushort*)Cv)[offc] = f2bf(gel);
        } else if constexpr (EPI == EPI_BIAS_RES_F32) {
          ((float*)Cv)[offc] = val + bias[col] + res[offc];
        } else if constexpr (EPI == EPI_PART_F32) {
          ((float*)Cv)[blockIdx.z * CBTCD + offc] = val;
        } else {
          float o = val + bias[col] + res[offc];
          ((float*)Cv)[offc] = o;
          C2[offc] = f2bf(o);
        }
      }
    }
  }
}

// ---------------- split-K reduce: out = p0 + p1 + bias + res ----------------
template <bool DUAL>
__global__ __launch_bounds__(256) void reduce2_k(const float* __restrict__ part,
                                                 const float* __restrict__ bias,
                                                 const float* __restrict__ res,
                                                 float* __restrict__ outf,
                                                 ushort* __restrict__ outb) {
  int i = blockIdx.x * 256 + threadIdx.x;  // float4 index over 4096x768
  float4 p0 = ((const float4*)part)[i];
  float4 p1 = ((const float4*)(part + CBTCD))[i];
  float4 rr = ((const float4*)res)[i];
  int col = (i * 4) % CD;
  float4 bb = *(const float4*)(bias + col);
  float4 o;
  o.x = p0.x + p1.x + rr.x + bb.x;
  o.y = p0.y + p1.y + rr.y + bb.y;
  o.z = p0.z + p1.z + rr.z + bb.z;
  o.w = p0.w + p1.w + rr.w + bb.w;
  ((float4*)outf)[i] = o;
  if constexpr (DUAL) {
    ushort4 u;
    u.x = f2bf(o.x); u.y = f2bf(o.y); u.z = f2bf(o.z); u.w = f2bf(o.w);
    ((ushort4*)outb)[i] = u;
  }
}

// ---------------- flash attention (swapped QK^T, in-register softmax) -----
// grid: (CT/64, CB*CH). block 256 = 4 waves; each wave owns 16 q rows (q=lr).
// Q is pre-scaled by 0.125*log2(e) (folded into Wq/bq), so S^T is already in
// exp2 domain. Lane (lg,lr) holds S^T[kv=j*16+lg*4+r][q=lr].
__global__ __launch_bounds__(256) void flash_k(const ushort* __restrict__ qkv,
                                               const ushort* __restrict__ vt,
                                               const unsigned* __restrict__ mbits,
                                               ushort* __restrict__ out) {
  const int q0 = blockIdx.x * 64;
  const int bh = blockIdx.y;
  const int b = bh / CH, h = bh % CH;
  const int tid = threadIdx.x;
  const int lane = tid & 63;
  const int wave = tid >> 6;
  const int lr = lane & 15;
  const int lg = lane >> 4;

  __shared__ ushort Ks[64][72];   // [kv][d]
  __shared__ ushort Vt[64][72];   // [e][kv]

  const int qg = q0 + wave * 16 + lr;  // this lane's q row
  const ushort* qrow = qkv + ((size_t)(b * CT) + qg) * 2304 + h * CDH;
  bf16x8 aq0 = *(const bf16x8*)(qrow + lg * 8);
  bf16x8 aq1 = *(const bf16x8*)(qrow + 32 + lg * 8);

  f32x4 acc[4] = {};              // O^T frags: acc[jj][r] = O^T[jj*16+lg*4+r][q=lr]
  float m_run = -1e30f, l_run = 0.f;

  const ushort* kbase = qkv + (size_t)(b * CT) * 2304 + CD + h * CDH;
  const ushort* vbase = vt + (size_t)bh * 64 * CT;

  for (int kv0 = 0; kv0 < CT; kv0 += 64) {
    __syncthreads();
#pragma unroll
    for (int p = 0; p < 2; ++p) {
      int i = p * 2048 + tid * 8;
      int r = i >> 6, c = i & 63;
      *(bf16x8*)(&Ks[r][c]) = *(const bf16x8*)(kbase + (size_t)(kv0 + r) * 2304 + c);
      *(bf16x8*)(&Vt[r][c]) = *(const bf16x8*)(vbase + (size_t)r * CT + kv0 + c);
    }
    __syncthreads();

    // S^T = K Q^T (4 tiles of 16 kv x 16 q), already exp2-domain scaled
    f32x4 st[4];
    __builtin_amdgcn_s_setprio(1);
#pragma unroll
    for (int j = 0; j < 4; ++j) {
      bf16x8 kf0 = *(const bf16x8*)(&Ks[j * 16 + lr][lg * 8]);
      bf16x8 kf1 = *(const bf16x8*)(&Ks[j * 16 + lr][32 + lg * 8]);
      f32x4 t = {};
      t = __builtin_amdgcn_mfma_f32_16x16x32_bf16(kf0, aq0, t, 0, 0, 0);
      t = __builtin_amdgcn_mfma_f32_16x16x32_bf16(kf1, aq1, t, 0, 0, 0);
      st[j] = t;
    }
    __builtin_amdgcn_s_setprio(0);

    // mask (all-ones fast path) + in-lane max over this lane's 16 kv values
    unsigned w0 = mbits[(size_t)qg * 64 + (kv0 >> 5)];
    unsigned w1 = mbits[(size_t)qg * 64 + (kv0 >> 5) + 1];
    float tmax = -INFINITY;
    if ((w0 & w1) == 0xFFFFFFFFu) {
#pragma unroll
      for (int j = 0; j < 4; ++j)
#pragma unroll
        for (int r = 0; r < 4; ++r) tmax = fmaxf(tmax, st[j][r]);
    } else {
#pragma unroll
      for (int j = 0; j < 4; ++j) {
        unsigned w = (j < 2) ? w0 : w1;
#pragma unroll
        for (int r = 0; r < 4; ++r) {
          int bit = (j * 16 + lg * 4 + r) & 31;
          if (((w >> bit) & 1u) == 0u) st[j][r] = -INFINITY;
          tmax = fmaxf(tmax, st[j][r]);
        }
      }
    }
    // cross-lane: q-row mates are lanes lr, lr+16, lr+32, lr+48
    tmax = fmaxf(tmax, __shfl_xor(tmax, 16));
    tmax = fmaxf(tmax, __shfl_xor(tmax, 32));

    // defer-rescale (T13): skip O/l rescale unless max grew by > 8 (log2)
    if (__any(tmax - m_run > 8.0f)) {
      float mnew = fmaxf(m_run, tmax);
      float sc = fexp2(m_run - mnew);
      m_run = mnew;
      l_run *= sc;
#pragma unroll
      for (int jj = 0; jj < 4; ++jj) {
        acc[jj][0] *= sc; acc[jj][1] *= sc; acc[jj][2] *= sc; acc[jj][3] *= sc;
      }
    }

    float tsum = 0.f;
    s16x4 pf[4];
#pragma unroll
    for (int j = 0; j < 4; ++j) {
      s16x4 pv;
#pragma unroll
      for (int r = 0; r < 4; ++r) {
        float p = fexp2(st[j][r] - m_run);
        tsum += p;
        pv[r] = (short)f2bf(p);
      }
      pf[j] = pv;
    }
    tsum += __shfl_xor(tsum, 16);
    tsum += __shfl_xor(tsum, 32);
    l_run += tsum;

    // PV: O^T[e][q] += V^T[e][kv] * P^T[kv][q], 16x16x16 mfma, K=16 per j
    __builtin_amdgcn_s_setprio(1);
#pragma unroll
    for (int jj = 0; jj < 4; ++jj) {
#pragma unroll
      for (int j = 0; j < 4; ++j) {
        s16x4 vf = *(const s16x4*)(&Vt[jj * 16 + lr][j * 16 + lg * 4]);
        acc[jj] = __builtin_amdgcn_mfma_f32_16x16x16bf16_1k(vf, pf[j], acc[jj], 0, 0, 0);
      }
    }
    __builtin_amdgcn_s_setprio(0);
  }

  // write O: lane holds O^T[e=jj*16+lg*4+r][q=lr] -> out[qg][h*64+e]
  float inv = 1.0f / l_run;
  const int orow = b * CT + qg;
#pragma unroll
  for (int jj = 0; jj < 4; ++jj) {
    u16x4 o;
#pragma unroll
    for (int r = 0; r < 4; ++r) o[r] = f2bf(acc[jj][r] * inv);
    *(u16x4*)(out + (size_t)orow * CD + h * CDH + jj * 16 + lg * 4) = o;
  }
}

// ---------------- V transpose: qkv V section -> vt [bh][e][t] ----------------
__global__ __launch_bounds__(256) void vtrans_k(const ushort* __restrict__ qkv,
                                                ushort* __restrict__ vt) {
  const int t0 = blockIdx.x * 64;
  const int bh = blockIdx.y;
  const int b = bh / CH, h = bh % CH;
  const int tid = threadIdx.x;
  __shared__ ushort tile[64][72];
#pragma unroll
  for (int p = 0; p < 2; ++p) {
    int i = p * 2048 + tid * 8;
    int tr = i >> 6, c = i & 63;
    *(bf16x8*)(&tile[tr][c]) =
        *(const bf16x8*)(qkv + (size_t)(b * CT + t0 + tr) * 2304 + 2 * CD + h * CDH + c);
  }
  __syncthreads();
#pragma unroll
  for (int p = 0; p < 2; ++p) {
    int i = p * 2048 + tid * 8;
    int er = i >> 6, tc = i & 63;
    ushort tmp[8];
#pragma unroll
    for (int j = 0; j < 8; ++j) tmp[j] = tile[tc + j][er];
    *(bf16x8*)(vt + (size_t)bh * 64 * CT + (size_t)er * CT + t0 + tc) = *(bf16x8*)tmp;
  }
}

// ---------------- mask -> bitmask ----------------
__global__ void maskbits_k(const int* __restrict__ mask, unsigned* __restrict__ mbits) {
  int idx = blockIdx.x * 256 + threadIdx.x;
  if (idx >= CT * 64) return;
  const int* mp = mask + (size_t)(idx >> 6) * CT + (idx & 63) * 32;
  unsigned bits = 0;
#pragma unroll
  for (int j = 0; j < 32; ++j) bits |= (mp[j] != 0 ? 1u : 0u) << j;
  mbits[idx] = bits;
}

// ---------------- layernorm ----------------
__global__ __launch_bounds__(256) void ln_k(const float* __restrict__ X,
                                            ushort* __restrict__ H,
                                            const float* __restrict__ g,
                                            const float* __restrict__ b) {
  const int t = blockIdx.x;
  const int tid = threadIdx.x;
  const float* row = X + (size_t)t * CD;
  float x0 = row[tid], x1 = row[tid + 256], x2 = row[tid + 512];
  float s = wred_sum(x0 + x1 + x2);
  __shared__ float sh[4], sh2[4];
  if ((tid & 63) == 0) sh[tid >> 6] = s;
  __syncthreads();
  float mu = (sh[0] + sh[1] + sh[2] + sh[3]) * (1.0f / 768.0f);
  float d0 = x0 - mu, d1 = x1 - mu, d2 = x2 - mu;
  float vs = wred_sum(d0 * d0 + d1 * d1 + d2 * d2);
  if ((tid & 63) == 0) sh2[tid >> 6] = vs;
  __syncthreads();
  float var = (sh2[0] + sh2[1] + sh2[2] + sh2[3]) * (1.0f / 768.0f);
  float r = 1.0f / sqrtf(var + 1e-5f);
  H[(size_t)t * CD + tid] = f2bf(d0 * r * g[tid] + b[tid]);
  H[(size_t)t * CD + tid + 256] = f2bf(d1 * r * g[tid + 256] + b[tid + 256]);
  H[(size_t)t * CD + tid + 512] = f2bf(d2 * r * g[tid + 512] + b[tid + 512]);
}

// ---------------- conversions / repacks ----------------
__global__ void f32_to_bf16_k(const float* __restrict__ in, ushort* __restrict__ out, int n4) {
  int i = blockIdx.x * 256 + threadIdx.x;
  if (i >= n4) return;
  float4 f = *(const float4*)(in + (size_t)i * 4);
  ushort4 u;
  u.x = f2bf(f.x); u.y = f2bf(f.y); u.z = f2bf(f.z); u.w = f2bf(f.w);
  *(ushort4*)(out + (size_t)i * 4) = u;
}

// tiled transpose + f32->bf16: src (z batches, [R][C] f32, stride sbs) ->
// dst (z batches, [C][R] bf16, stride dbs). R, C multiples of 32.
__global__ __launch_bounds__(256) void tcvt_k(const float* __restrict__ src, size_t sbs,
                                              ushort* __restrict__ dst, size_t dbs,
                                              int R, int C, float scale) {
  __shared__ float t[32][33];
  const float* s = src + blockIdx.z * sbs;
  ushort* d = dst + blockIdx.z * dbs;
  const int tx = threadIdx.x & 31;
  const int ty4 = (threadIdx.x >> 5) * 4;
  const int r0 = blockIdx.y * 32, c0 = blockIdx.x * 32;
#pragma unroll
  for (int i = 0; i < 4; ++i) t[ty4 + i][tx] = s[(size_t)(r0 + ty4 + i) * C + c0 + tx];
  __syncthreads();
#pragma unroll
  for (int i = 0; i < 4; ++i)
    d[(size_t)(c0 + ty4 + i) * R + r0 + tx] = f2bf(t[tx][ty4 + i] * scale);
}

// bq/bk/bv (L,H,DH) -> bqkv (L, 2304) fp32; bq scaled by QSCALE
__global__ void repack_bqkv_k(const float* __restrict__ bq, const float* __restrict__ bk,
                              const float* __restrict__ bv, float* __restrict__ dst) {
  int idx = blockIdx.x * 256 + threadIdx.x;
  if (idx >= CL * 2304) return;
  int l = idx / 2304;
  int c = idx % 2304;
  int sec = c / CD;
  int within = c % CD;
  int h = within / CDH;
  int e = within % CDH;
  const float* B = (sec == 0) ? bq : ((sec == 1) ? bk : bv);
  float v = B[((size_t)l * CH + h) * CDH + e];
  if (sec == 0) v *= QSCALE;
  dst[idx] = v;
}

extern "C" void kernel_launch(void* const* d_in, const int* in_sizes, int n_in,
                              void* d_out, int out_size, void* d_ws, size_t ws_size,
                              hipStream_t stream) {
  (void)in_sizes; (void)n_in; (void)out_size; (void)ws_size;
  const float* X = (const float*)d_in[0];
  const int* MSK = (const int*)d_in[1];
  const float* Wq = (const float*)d_in[2];
  const float* bq = (const float*)d_in[3];
  const float* Wk = (const float*)d_in[4];
  const float* bk = (const float*)d_in[5];
  const float* Wv = (const float*)d_in[6];
  const float* bv = (const float*)d_in[7];
  const float* Wo = (const float*)d_in[8];
  const float* bo = (const float*)d_in[9];
  const float* lng = (const float*)d_in[10];
  const float* lnb = (const float*)d_in[11];
  const float* W1 = (const float*)d_in[12];
  const float* b1 = (const float*)d_in[13];
  const float* W2 = (const float*)d_in[14];
  const float* b2 = (const float*)d_in[15];

  char* base = (char*)d_ws;
  size_t off = 0;
  auto alloc = [&](size_t bytes) {
    char* p = base + off;
    off = (off + bytes + 255) & ~(size_t)255;
    return p;
  };
  ushort* wqkv_t = (ushort*)alloc((size_t)CL * 2304 * CD * 2);
  ushort* wo_t = (ushort*)alloc((size_t)CL * CD * CD * 2);
  ushort* w1_t = (ushort*)alloc((size_t)CL * CF * CD * 2);
  ushort* w2_t = (ushort*)alloc((size_t)CL * CD * CF * 2);
  float* bqkv = (float*)alloc((size_t)CL * 2304 * 4);
  ushort* xb = (ushort*)alloc((size_t)CB * CT * CD * 2);
  ushort* qkv = (ushort*)alloc((size_t)CB * CT * 2304 * 2);   // 18.87 MB
  ushort* vt = (ushort*)alloc((size_t)CB * CH * CDH * CT * 2); // 6.29 MB, contiguous after qkv
  unsigned* mbits = (unsigned*)alloc((size_t)CT * 64 * 4);
  ushort* attno = (ushort*)alloc((size_t)CB * CT * CD * 2);
  float* xattn = (float*)alloc((size_t)CB * CT * CD * 4);
  float* xf = (float*)alloc((size_t)CB * CT * CD * 4);
  ushort* hln = (ushort*)alloc((size_t)CB * CT * CD * 2);
  ushort* gbuf = (ushort*)alloc((size_t)CB * CT * CF * 2);
  // split-K partials (2 x 4096 x 768 f32 = 25.17 MB) alias the qkv+vt region:
  // qkv/vt are dead by FFN2 time and rewritten next layer after the reduce.
  float* part = (float*)qkv;

  const int BT_ = CB * CT;  // 4096 rows

  // ---- one-time weight repacks (coalesced tiled transposes) ----
  for (int l = 0; l < CL; ++l) {
    // Wq/Wk/Wv [H][768][64] -> wqkv_t rows sec*768 + h*64 + e, cols d
    tcvt_k<<<dim3(CDH / 32, CD / 32, CH), 256, 0, stream>>>(
        Wq + (size_t)l * CH * CD * CDH, (size_t)CD * CDH,
        wqkv_t + (size_t)l * 2304 * CD + 0 * CD * CD, (size_t)CDH * CD,
        CD, CDH, QSCALE);
    tcvt_k<<<dim3(CDH / 32, CD / 32, CH), 256, 0, stream>>>(
        Wk + (size_t)l * CH * CD * CDH, (size_t)CD * CDH,
        wqkv_t + (size_t)l * 2304 * CD + 1 * CD * CD, (size_t)CDH * CD,
        CD, CDH, 1.0f);
    tcvt_k<<<dim3(CDH / 32, CD / 32, CH), 256, 0, stream>>>(
        Wv + (size_t)l * CH * CD * CDH, (size_t)CD * CDH,
        wqkv_t + (size_t)l * 2304 * CD + 2 * CD * CD, (size_t)CDH * CD,
        CD, CDH, 1.0f);
  }
  // Wo [768][768] -> [768][768]^T, both layers batched
  tcvt_k<<<dim3(CD / 32, CD / 32, CL), 256, 0, stream>>>(
      Wo, (size_t)CD * CD, wo_t, (size_t)CD * CD, CD, CD, 1.0f);
  // W1 [768][3072] -> [3072][768]
  tcvt_k<<<dim3(CF / 32, CD / 32, CL), 256, 0, stream>>>(
      W1, (size_t)CD * CF, w1_t, (size_t)CF * CD, CD, CF, 1.0f);
  // W2 [3072][768] -> [768][3072]
  tcvt_k<<<dim3(CD / 32, CF / 32, CL), 256, 0, stream>>>(
      W2, (size_t)CF * CD, w2_t, (size_t)CD * CF, CF, CD, 1.0f);
  {
    int n = CL * 2304;
    repack_bqkv_k<<<(n + 255) / 256, 256, 0, stream>>>(bq, bk, bv, bqkv);
  }
  maskbits_k<<<(CT * 64 + 255) / 256, 256, 0, stream>>>(MSK, mbits);

  // layer-0 input -> bf16 (layer 1 gets it fused from FFN2's reduce)
  {
    int n4 = BT_ * CD / 4;
    f32_to_bf16_k<<<(n4 + 255) / 256, 256, 0, stream>>>(X, xb, n4);
  }

  for (int l = 0; l < CL; ++l) {
    const float* xcur = (l == 0) ? X : xf;
    // QKV projection: (4096x768) @ (768x2304) + bias -> qkv bf16
    gemm_k<EPI_BIAS_BF16><<<dim3(2304 / 128, BT_ / 128), 256, 0, stream>>>(
        xb, CD, wqkv_t + (size_t)l * 2304 * CD, CD, qkv, 2304, CD,
        bqkv + (size_t)l * 2304, nullptr, nullptr);
    // V transpose + fused flash attention
    vtrans_k<<<dim3(CT / 64, CB * CH), 256, 0, stream>>>(qkv, vt);
    flash_k<<<dim3(CT / 64, CB * CH), 256, 0, stream>>>(qkv, vt, mbits, attno);
    // output projection + bias + residual -> xattn (fp32)
    gemm_k<EPI_BIAS_RES_F32><<<dim3(CD / 128, BT_ / 128), 256, 0, stream>>>(
        attno, CD, wo_t + (size_t)l * CD * CD, CD, xattn, CD, CD,
        bo + (size_t)l * CD, xcur, nullptr);
    // layernorm -> hln bf16
    ln_k<<<BT_, 256, 0, stream>>>(xattn, hln, lng + (size_t)l * CD, lnb + (size_t)l * CD);
    // FFN1 + bias + gelu -> gbuf bf16
    gemm_k<EPI_BIAS_GELU_BF16><<<dim3(CF / 128, BT_ / 128), 256, 0, stream>>>(
        hln, CD, w1_t + (size_t)l * CF * CD, CD, gbuf, CF, CD,
        b1 + (size_t)l * CF, nullptr, nullptr);
    // FFN2 split-K=2 (fills the 192-block grid hole) -> f32 partials
    gemm_k<EPI_PART_F32><<<dim3(CD / 128, BT_ / 128, 2), 256, 0, stream>>>(
        gbuf, CF, w2_t + (size_t)l * CD * CF, CF, part, CD, CF / 2,
        nullptr, nullptr, nullptr);
    // reduce partials + bias + residual -> xf (+ bf16 xb) or d_out
    const int nred = BT_ * CD / 4 / 256;  // 3072 blocks
    if (l == CL - 1) {
      reduce2_k<false><<<nred, 256, 0, stream>>>(part, b2 + (size_t)l * CD, xattn,
                                                 (float*)d_out, nullptr);
    } else {
      reduce2_k<true><<<nred, 256, 0, stream>>>(part, b2 + (size_t)l * CD, xattn,
                                                xf, xb);
    }
  }
}

// Round 6
// 438.511 us; speedup vs baseline: 14.5628x; 1.0040x over previous
//
#include <hip/hip_runtime.h>
#include <math.h>

// Problem constants
#define CL 2
#define CH 12
#define CD 768
#define CDH 64
#define CF 3072
#define CB 2
#define CT 2048
#define CBTCD ((size_t)CB * CT * CD)

typedef __bf16 bf16x8 __attribute__((ext_vector_type(8)));
typedef float f32x4 __attribute__((ext_vector_type(4)));
typedef short s16x4 __attribute__((ext_vector_type(4)));
typedef ushort u16x4 __attribute__((ext_vector_type(4)));

// 0.125 * log2(e): folded into Wq/bq so QK^T lands in exp2 domain
#define QSCALE 0.18033688011112042f

__device__ __forceinline__ ushort f2bf(float f) {
  return __builtin_bit_cast(ushort, (__bf16)f);
}

__device__ __forceinline__ float fexp2(float x) {
  float r;
  asm volatile("v_exp_f32 %0, %1" : "=v"(r) : "v"(x));
  return r;
}

__device__ __forceinline__ float wred_sum(float v) {
#pragma unroll
  for (int o = 32; o > 0; o >>= 1) v += __shfl_xor(v, o);
  return v;
}

// async global->LDS, 16B per lane. LDS dest = wave-uniform base + lane*16.
__device__ __forceinline__ void gload16(const ushort* g, ushort* l) {
  __builtin_amdgcn_global_load_lds(
      (const __attribute__((address_space(1))) unsigned int*)g,
      (__attribute__((address_space(3))) unsigned int*)l, 16, 0, 0);
}

// ---------------- GEMM (m97 structure + dbuf pipeline + XCD swizzle) ------
// C(MxN) = A(MxK) @ B, A bf16 row-major (lda), B stored (N x K) row-major (ldb).
// REQUIRES: M % 128 == 0, N % 128 == 0, K % 64 == 0, (gridX*gridY) % 8 == 0.
// blockIdx.z = K-split index (K = per-split K); EPI_PART_F32 writes f32
// partials at part[z * CBTCD + row*ldc + col].
enum { EPI_BF16 = 1, EPI_BIAS_BF16 = 2, EPI_BIAS_GELU_BF16 = 3, EPI_BIAS_RES_F32 = 4, EPI_BIAS_RES_F32_BF16 = 5, EPI_PART_F32 = 6 };

template <int EPI>
__global__ __launch_bounds__(256) void gemm_k(
    const ushort* __restrict__ A, int lda,
    const ushort* __restrict__ B, int ldb,
    void* __restrict__ Cv, int ldc,
    int K,
    const float* __restrict__ bias,
    const float* __restrict__ res,
    ushort* __restrict__ C2) {
  __shared__ ushort As[2][128 * 32];
  __shared__ ushort Bs[2][128 * 32];
  const int tid = threadIdx.x;
  const int lane = tid & 63;
  const int wave = tid >> 6;
  const int wm = (wave >> 1) * 64;
  const int wn = (wave & 1) * 64;

  // bijective XCD swizzle (gridX*gridY multiple of 8)
  const int gx = gridDim.x;
  const int nwg = gx * gridDim.y;
  int wgid = blockIdx.y * gx + blockIdx.x;
  const int cpx = nwg >> 3;
  wgid = (wgid & 7) * cpx + (wgid >> 3);
  const int m0 = (wgid / gx) * 128;
  const int n0 = (wgid % gx) * 128;

  const int lr = lane & 15;
  const int lg = lane >> 4;
  f32x4 acc[4][4] = {};

  const int kz = blockIdx.z * K;  // K-split offset (0 for non-split launches)
  const ushort* pa = A + (size_t)(m0 + (tid >> 2)) * lda + (tid & 3) * 8 + kz;
  const ushort* pb = B + (size_t)(n0 + (tid >> 2)) * ldb + (tid & 3) * 8 + kz;

  auto stage = [&](int buf, int k0) {
#pragma unroll
    for (int p = 0; p < 2; ++p) {
      gload16(pa + (size_t)p * 64 * lda + k0, &As[buf][wave * 512 + p * 2048]);
      gload16(pb + (size_t)p * 64 * ldb + k0, &Bs[buf][wave * 512 + p * 2048]);
    }
  };

  const int nt = K >> 5;
  stage(0, 0);
  for (int kt = 0; kt < nt; ++kt) {
    const int cur = kt & 1;
    if (kt + 1 < nt) {
      stage(cur ^ 1, (kt + 1) << 5);
      asm volatile("s_waitcnt vmcnt(4)" ::: "memory");
    } else {
      asm volatile("s_waitcnt vmcnt(0)" ::: "memory");
    }
    __builtin_amdgcn_s_barrier();
    __builtin_amdgcn_sched_barrier(0);

    bf16x8 af[4], bfr[4];
#pragma unroll
    for (int f = 0; f < 4; ++f) af[f] = *(const bf16x8*)(&As[cur][(wm + f * 16 + lr) * 32 + lg * 8]);
#pragma unroll
    for (int f = 0; f < 4; ++f) bfr[f] = *(const bf16x8*)(&Bs[cur][(wn + f * 16 + lr) * 32 + lg * 8]);
#pragma unroll
    for (int i = 0; i < 4; ++i)
#pragma unroll
      for (int j = 0; j < 4; ++j)
        acc[i][j] = __builtin_amdgcn_mfma_f32_16x16x32_bf16(af[i], bfr[j], acc[i][j], 0, 0, 0);

    __builtin_amdgcn_sched_barrier(0);
    __builtin_amdgcn_s_barrier();
  }

  // epilogue: lane holds D[row=(lane>>4)*4+r][col=lane&15] per frag
  const int cr0 = lg * 4;
#pragma unroll
  for (int i = 0; i < 4; ++i) {
#pragma unroll
    for (int j = 0; j < 4; ++j) {
      int col = n0 + wn + j * 16 + lr;
#pragma unroll
      for (int r = 0; r < 4; ++r) {
        int row = m0 + wm + i * 16 + cr0 + r;
        float val = acc[i][j][r];
        size_t offc = (size_t)row * ldc + col;
        if constexpr (EPI == EPI_BF16) {
          ((ushort*)Cv)[offc] = f2bf(val);
        } else if constexpr (EPI == EPI_BIAS_BF16) {
          ((ushort*)Cv)[offc] = f2bf(val + bias[col]);
        } else if constexpr (EPI == EPI_BIAS_GELU_BF16) {
          float x = val + bias[col];
          float gel = 0.5f * x * (1.0f + erff(x * 0.70710678118654752f));
          ((ushort*)Cv)[offc] = f2bf(gel);
        } else if constexpr (EPI == EPI_BIAS_RES_F32) {
          ((float*)Cv)[offc] = val + bias[col] + res[offc];
        } else if constexpr (EPI == EPI_PART_F32) {
          ((float*)Cv)[blockIdx.z * CBTCD + offc] = val;
        } else {
          float o = val + bias[col] + res[offc];
          ((float*)Cv)[offc] = o;
          C2[offc] = f2bf(o);
        }
      }
    }
  }
}

// ---------------- split-K reduce: out = p0 + p1 + bias + res ----------------
template <bool DUAL>
__global__ __launch_bounds__(256) void reduce2_k(const float* __restrict__ part,
                                                 const float* __restrict__ bias,
                                                 const float* __restrict__ res,
                                                 float* __restrict__ outf,
                                                 ushort* __restrict__ outb) {
  int i = blockIdx.x * 256 + threadIdx.x;  // float4 index over 4096x768
  float4 p0 = ((const float4*)part)[i];
  float4 p1 = ((const float4*)(part + CBTCD))[i];
  float4 rr = ((const float4*)res)[i];
  int col = (i * 4) % CD;
  float4 bb = *(const float4*)(bias + col);
  float4 o;
  o.x = p0.x + p1.x + rr.x + bb.x;
  o.y = p0.y + p1.y + rr.y + bb.y;
  o.z = p0.z + p1.z + rr.z + bb.z;
  o.w = p0.w + p1.w + rr.w + bb.w;
  ((float4*)outf)[i] = o;
  if constexpr (DUAL) {
    ushort4 u;
    u.x = f2bf(o.x); u.y = f2bf(o.y); u.z = f2bf(o.z); u.w = f2bf(o.w);
    ((ushort4*)outb)[i] = u;
  }
}

// ---------------- flash attention (swapped QK^T, in-register softmax,
//                  T14 register-prefetch staging) ----------------
// grid: (CT/64, CB*CH). block 256 = 4 waves; each wave owns 16 q rows (q=lr).
// Q is pre-scaled by 0.125*log2(e) (folded into Wq/bq), so S^T is already in
// exp2 domain. Lane (lg,lr) holds S^T[kv=j*16+lg*4+r][q=lr].
__global__ __launch_bounds__(256) void flash_k(const ushort* __restrict__ qkv,
                                               const ushort* __restrict__ vt,
                                               const unsigned* __restrict__ mbits,
                                               ushort* __restrict__ out) {
  const int q0 = blockIdx.x * 64;
  const int bh = blockIdx.y;
  const int b = bh / CH, h = bh % CH;
  const int tid = threadIdx.x;
  const int lane = tid & 63;
  const int wave = tid >> 6;
  const int lr = lane & 15;
  const int lg = lane >> 4;

  __shared__ ushort Ks[64][72];   // [kv][d]
  __shared__ ushort Vt[64][72];   // [e][kv]

  const int qg = q0 + wave * 16 + lr;  // this lane's q row
  const ushort* qrow = qkv + ((size_t)(b * CT) + qg) * 2304 + h * CDH;
  bf16x8 aq0 = *(const bf16x8*)(qrow + lg * 8);
  bf16x8 aq1 = *(const bf16x8*)(qrow + 32 + lg * 8);

  f32x4 acc[4] = {};              // O^T frags: acc[jj][r] = O^T[jj*16+lg*4+r][q=lr]
  float m_run = -1e30f, l_run = 0.f;  // l_run: per-LANE partial (mates share m)

  const ushort* kbase = qkv + (size_t)(b * CT) * 2304 + CD + h * CDH;
  const ushort* vbase = vt + (size_t)bh * 64 * CT;

  // staging slice: rows r0/r1, col cc (64x64 K tile + 64x64 Vt tile)
  const int r0 = tid >> 3, r1 = 32 + (tid >> 3), cc = (tid & 7) * 8;

  auto ld = [&](int kv0, bf16x8& k0, bf16x8& k1, bf16x8& v0, bf16x8& v1) {
    k0 = *(const bf16x8*)(kbase + (size_t)(kv0 + r0) * 2304 + cc);
    k1 = *(const bf16x8*)(kbase + (size_t)(kv0 + r1) * 2304 + cc);
    v0 = *(const bf16x8*)(vbase + (size_t)r0 * CT + kv0 + cc);
    v1 = *(const bf16x8*)(vbase + (size_t)r1 * CT + kv0 + cc);
  };
  auto st = [&](bf16x8 k0, bf16x8 k1, bf16x8 v0, bf16x8 v1) {
    *(bf16x8*)(&Ks[r0][cc]) = k0;
    *(bf16x8*)(&Ks[r1][cc]) = k1;
    *(bf16x8*)(&Vt[r0][cc]) = v0;
    *(bf16x8*)(&Vt[r1][cc]) = v1;
  };

  auto compute = [&](int kv0) {
    // S^T = K Q^T (4 tiles of 16 kv x 16 q), already exp2-domain scaled
    f32x4 stt[4];
    __builtin_amdgcn_s_setprio(1);
#pragma unroll
    for (int j = 0; j < 4; ++j) {
      bf16x8 kf0 = *(const bf16x8*)(&Ks[j * 16 + lr][lg * 8]);
      bf16x8 kf1 = *(const bf16x8*)(&Ks[j * 16 + lr][32 + lg * 8]);
      f32x4 t = {};
      t = __builtin_amdgcn_mfma_f32_16x16x32_bf16(kf0, aq0, t, 0, 0, 0);
      t = __builtin_amdgcn_mfma_f32_16x16x32_bf16(kf1, aq1, t, 0, 0, 0);
      stt[j] = t;
    }
    __builtin_amdgcn_s_setprio(0);

    // mask (all-ones fast path) + in-lane max over this lane's 16 kv values
    unsigned w0 = mbits[(size_t)qg * 64 + (kv0 >> 5)];
    unsigned w1 = mbits[(size_t)qg * 64 + (kv0 >> 5) + 1];
    float tmax = -INFINITY;
    if ((w0 & w1) == 0xFFFFFFFFu) {
#pragma unroll
      for (int j = 0; j < 4; ++j)
#pragma unroll
        for (int r = 0; r < 4; ++r) tmax = fmaxf(tmax, stt[j][r]);
    } else {
#pragma unroll
      for (int j = 0; j < 4; ++j) {
        unsigned w = (j < 2) ? w0 : w1;
#pragma unroll
        for (int r = 0; r < 4; ++r) {
          int bit = (j * 16 + lg * 4 + r) & 31;
          if (((w >> bit) & 1u) == 0u) stt[j][r] = -INFINITY;
          tmax = fmaxf(tmax, stt[j][r]);
        }
      }
    }
    // cross-lane: q-row mates are lanes lr, lr+16, lr+32, lr+48
    tmax = fmaxf(tmax, __shfl_xor(tmax, 16));
    tmax = fmaxf(tmax, __shfl_xor(tmax, 32));

    // defer-rescale (T13): skip O/l rescale unless max grew by > 8 (log2)
    if (__any(tmax - m_run > 8.0f)) {
      float mnew = fmaxf(m_run, tmax);
      float sc = fexp2(m_run - mnew);
      m_run = mnew;
      l_run *= sc;
#pragma unroll
      for (int jj = 0; jj < 4; ++jj) {
        acc[jj][0] *= sc; acc[jj][1] *= sc; acc[jj][2] *= sc; acc[jj][3] *= sc;
      }
    }

    s16x4 pf[4];
#pragma unroll
    for (int j = 0; j < 4; ++j) {
      s16x4 pv;
#pragma unroll
      for (int r = 0; r < 4; ++r) {
        float p = fexp2(stt[j][r] - m_run);
        l_run += p;
        pv[r] = (short)f2bf(p);
      }
      pf[j] = pv;
    }

    // PV: O^T[e][q] += V^T[e][kv] * P^T[kv][q], 16x16x16 mfma, K=16 per j
    __builtin_amdgcn_s_setprio(1);
#pragma unroll
    for (int jj = 0; jj < 4; ++jj) {
#pragma unroll
      for (int j = 0; j < 4; ++j) {
        s16x4 vf = *(const s16x4*)(&Vt[jj * 16 + lr][j * 16 + lg * 4]);
        acc[jj] = __builtin_amdgcn_mfma_f32_16x16x16bf16_1k(vf, pf[j], acc[jj], 0, 0, 0);
      }
    }
    __builtin_amdgcn_s_setprio(0);
  };

  // main loop: 2 kv-tiles per iteration, register ping-pong prefetch (T14).
  // Two barriers per tile make write-after-read safe with a single LDS buffer;
  // the prefetch loads issue one tile early so HBM/L2 latency hides under
  // the previous tile's QK^T/softmax/PV.
  bf16x8 ka0, ka1, va0, va1, kb0, kb1, vb0, vb1;
  ld(0, ka0, ka1, va0, va1);
  for (int kv0 = 0; kv0 < CT; kv0 += 128) {
    __syncthreads();
    st(ka0, ka1, va0, va1);
    __syncthreads();
    ld(kv0 + 64, kb0, kb1, vb0, vb1);
    compute(kv0);
    __syncthreads();
    st(kb0, kb1, vb0, vb1);
    __syncthreads();
    if (kv0 + 128 < CT) ld(kv0 + 128, ka0, ka1, va0, va1);
    compute(kv0 + 64);
  }

  // final cross-lane reduce of per-lane l partials (mates lr, +16, +32, +48)
  l_run += __shfl_xor(l_run, 16);
  l_run += __shfl_xor(l_run, 32);

  // write O: lane holds O^T[e=jj*16+lg*4+r][q=lr] -> out[qg][h*64+e]
  float inv = 1.0f / l_run;
  const int orow = b * CT + qg;
#pragma unroll
  for (int jj = 0; jj < 4; ++jj) {
    u16x4 o;
#pragma unroll
    for (int r = 0; r < 4; ++r) o[r] = f2bf(acc[jj][r] * inv);
    *(u16x4*)(out + (size_t)orow * CD + h * CDH + jj * 16 + lg * 4) = o;
  }
}

// ---------------- V transpose: qkv V section -> vt [bh][e][t] ----------------
__global__ __launch_bounds__(256) void vtrans_k(const ushort* __restrict__ qkv,
                                                ushort* __restrict__ vt) {
  const int t0 = blockIdx.x * 64;
  const int bh = blockIdx.y;
  const int b = bh / CH, h = bh % CH;
  const int tid = threadIdx.x;
  __shared__ ushort tile[64][72];
#pragma unroll
  for (int p = 0; p < 2; ++p) {
    int i = p * 2048 + tid * 8;
    int tr = i >> 6, c = i & 63;
    *(bf16x8*)(&tile[tr][c]) =
        *(const bf16x8*)(qkv + (size_t)(b * CT + t0 + tr) * 2304 + 2 * CD + h * CDH + c);
  }
  __syncthreads();
#pragma unroll
  for (int p = 0; p < 2; ++p) {
    int i = p * 2048 + tid * 8;
    int er = i >> 6, tc = i & 63;
    ushort tmp[8];
#pragma unroll
    for (int j = 0; j < 8; ++j) tmp[j] = tile[tc + j][er];
    *(bf16x8*)(vt + (size_t)bh * 64 * CT + (size_t)er * CT + t0 + tc) = *(bf16x8*)tmp;
  }
}

// ---------------- mask -> bitmask ----------------
__global__ void maskbits_k(const int* __restrict__ mask, unsigned* __restrict__ mbits) {
  int idx = blockIdx.x * 256 + threadIdx.x;
  if (idx >= CT * 64) return;
  const int* mp = mask + (size_t)(idx >> 6) * CT + (idx & 63) * 32;
  unsigned bits = 0;
#pragma unroll
  for (int j = 0; j < 32; ++j) bits |= (mp[j] != 0 ? 1u : 0u) << j;
  mbits[idx] = bits;
}

// ---------------- layernorm ----------------
__global__ __launch_bounds__(256) void ln_k(const float* __restrict__ X,
                                            ushort* __restrict__ H,
                                            const float* __restrict__ g,
                                            const float* __restrict__ b) {
  const int t = blockIdx.x;
  const int tid = threadIdx.x;
  const float* row = X + (size_t)t * CD;
  float x0 = row[tid], x1 = row[tid + 256], x2 = row[tid + 512];
  float s = wred_sum(x0 + x1 + x2);
  __shared__ float sh[4], sh2[4];
  if ((tid & 63) == 0) sh[tid >> 6] = s;
  __syncthreads();
  float mu = (sh[0] + sh[1] + sh[2] + sh[3]) * (1.0f / 768.0f);
  float d0 = x0 - mu, d1 = x1 - mu, d2 = x2 - mu;
  float vs = wred_sum(d0 * d0 + d1 * d1 + d2 * d2);
  if ((tid & 63) == 0) sh2[tid >> 6] = vs;
  __syncthreads();
  float var = (sh2[0] + sh2[1] + sh2[2] + sh2[3]) * (1.0f / 768.0f);
  float r = 1.0f / sqrtf(var + 1e-5f);
  H[(size_t)t * CD + tid] = f2bf(d0 * r * g[tid] + b[tid]);
  H[(size_t)t * CD + tid + 256] = f2bf(d1 * r * g[tid + 256] + b[tid + 256]);
  H[(size_t)t * CD + tid + 512] = f2bf(d2 * r * g[tid + 512] + b[tid + 512]);
}

// ---------------- conversions / repacks ----------------
__global__ void f32_to_bf16_k(const float* __restrict__ in, ushort* __restrict__ out, int n4) {
  int i = blockIdx.x * 256 + threadIdx.x;
  if (i >= n4) return;
  float4 f = *(const float4*)(in + (size_t)i * 4);
  ushort4 u;
  u.x = f2bf(f.x); u.y = f2bf(f.y); u.z = f2bf(f.z); u.w = f2bf(f.w);
  *(ushort4*)(out + (size_t)i * 4) = u;
}

// tiled transpose + f32->bf16: src (z batches, [R][C] f32, stride sbs) ->
// dst (z batches, [C][R] bf16, stride dbs). R, C multiples of 32.
__global__ __launch_bounds__(256) void tcvt_k(const float* __restrict__ src, size_t sbs,
                                              ushort* __restrict__ dst, size_t dbs,
                                              int R, int C, float scale) {
  __shared__ float t[32][33];
  const float* s = src + blockIdx.z * sbs;
  ushort* d = dst + blockIdx.z * dbs;
  const int tx = threadIdx.x & 31;
  const int ty4 = (threadIdx.x >> 5) * 4;
  const int r0 = blockIdx.y * 32, c0 = blockIdx.x * 32;
#pragma unroll
  for (int i = 0; i < 4; ++i) t[ty4 + i][tx] = s[(size_t)(r0 + ty4 + i) * C + c0 + tx];
  __syncthreads();
#pragma unroll
  for (int i = 0; i < 4; ++i)
    d[(size_t)(c0 + ty4 + i) * R + r0 + tx] = f2bf(t[tx][ty4 + i] * scale);
}

// bq/bk/bv (L,H,DH) -> bqkv (L, 2304) fp32; bq scaled by QSCALE
__global__ void repack_bqkv_k(const float* __restrict__ bq, const float* __restrict__ bk,
                              const float* __restrict__ bv, float* __restrict__ dst) {
  int idx = blockIdx.x * 256 + threadIdx.x;
  if (idx >= CL * 2304) return;
  int l = idx / 2304;
  int c = idx % 2304;
  int sec = c / CD;
  int within = c % CD;
  int h = within / CDH;
  int e = within % CDH;
  const float* B = (sec == 0) ? bq : ((sec == 1) ? bk : bv);
  float v = B[((size_t)l * CH + h) * CDH + e];
  if (sec == 0) v *= QSCALE;
  dst[idx] = v;
}

extern "C" void kernel_launch(void* const* d_in, const int* in_sizes, int n_in,
                              void* d_out, int out_size, void* d_ws, size_t ws_size,
                              hipStream_t stream) {
  (void)in_sizes; (void)n_in; (void)out_size; (void)ws_size;
  const float* X = (const float*)d_in[0];
  const int* MSK = (const int*)d_in[1];
  const float* Wq = (const float*)d_in[2];
  const float* bq = (const float*)d_in[3];
  const float* Wk = (const float*)d_in[4];
  const float* bk = (const float*)d_in[5];
  const float* Wv = (const float*)d_in[6];
  const float* bv = (const float*)d_in[7];
  const float* Wo = (const float*)d_in[8];
  const float* bo = (const float*)d_in[9];
  const float* lng = (const float*)d_in[10];
  const float* lnb = (const float*)d_in[11];
  const float* W1 = (const float*)d_in[12];
  const float* b1 = (const float*)d_in[13];
  const float* W2 = (const float*)d_in[14];
  const float* b2 = (const float*)d_in[15];

  char* base = (char*)d_ws;
  size_t off = 0;
  auto alloc = [&](size_t bytes) {
    char* p = base + off;
    off = (off + bytes + 255) & ~(size_t)255;
    return p;
  };
  ushort* wqkv_t = (ushort*)alloc((size_t)CL * 2304 * CD * 2);
  ushort* wo_t = (ushort*)alloc((size_t)CL * CD * CD * 2);
  ushort* w1_t = (ushort*)alloc((size_t)CL * CF * CD * 2);
  ushort* w2_t = (ushort*)alloc((size_t)CL * CD * CF * 2);
  float* bqkv = (float*)alloc((size_t)CL * 2304 * 4);
  ushort* xb = (ushort*)alloc((size_t)CB * CT * CD * 2);
  ushort* qkv = (ushort*)alloc((size_t)CB * CT * 2304 * 2);   // 18.87 MB
  ushort* vt = (ushort*)alloc((size_t)CB * CH * CDH * CT * 2); // 6.29 MB, contiguous after qkv
  unsigned* mbits = (unsigned*)alloc((size_t)CT * 64 * 4);
  ushort* attno = (ushort*)alloc((size_t)CB * CT * CD * 2);
  float* xattn = (float*)alloc((size_t)CB * CT * CD * 4);
  float* xf = (float*)alloc((size_t)CB * CT * CD * 4);
  ushort* hln = (ushort*)alloc((size_t)CB * CT * CD * 2);
  ushort* gbuf = (ushort*)alloc((size_t)CB * CT * CF * 2);
  // split-K partials (2 x 4096 x 768 f32 = 25.17 MB) alias the qkv+vt region:
  // qkv/vt are dead by FFN2 time and rewritten next layer after the reduce.
  float* part = (float*)qkv;

  const int BT_ = CB * CT;  // 4096 rows

  // ---- one-time weight repacks (coalesced tiled transposes) ----
  for (int l = 0; l < CL; ++l) {
    // Wq/Wk/Wv [H][768][64] -> wqkv_t rows sec*768 + h*64 + e, cols d
    tcvt_k<<<dim3(CDH / 32, CD / 32, CH), 256, 0, stream>>>(
        Wq + (size_t)l * CH * CD * CDH, (size_t)CD * CDH,
        wqkv_t + (size_t)l * 2304 * CD + 0 * CD * CD, (size_t)CDH * CD,
        CD, CDH, QSCALE);
    tcvt_k<<<dim3(CDH / 32, CD / 32, CH), 256, 0, stream>>>(
        Wk + (size_t)l * CH * CD * CDH, (size_t)CD * CDH,
        wqkv_t + (size_t)l * 2304 * CD + 1 * CD * CD, (size_t)CDH * CD,
        CD, CDH, 1.0f);
    tcvt_k<<<dim3(CDH / 32, CD / 32, CH), 256, 0, stream>>>(
        Wv + (size_t)l * CH * CD * CDH, (size_t)CD * CDH,
        wqkv_t + (size_t)l * 2304 * CD + 2 * CD * CD, (size_t)CDH * CD,
        CD, CDH, 1.0f);
  }
  // Wo [768][768] -> [768][768]^T, both layers batched
  tcvt_k<<<dim3(CD / 32, CD / 32, CL), 256, 0, stream>>>(
      Wo, (size_t)CD * CD, wo_t, (size_t)CD * CD, CD, CD, 1.0f);
  // W1 [768][3072] -> [3072][768]
  tcvt_k<<<dim3(CF / 32, CD / 32, CL), 256, 0, stream>>>(
      W1, (size_t)CD * CF, w1_t, (size_t)CF * CD, CD, CF, 1.0f);
  // W2 [3072][768] -> [768][3072]
  tcvt_k<<<dim3(CD / 32, CF / 32, CL), 256, 0, stream>>>(
      W2, (size_t)CF * CD, w2_t, (size_t)CD * CF, CF, CD, 1.0f);
  {
    int n = CL * 2304;
    repack_bqkv_k<<<(n + 255) / 256, 256, 0, stream>>>(bq, bk, bv, bqkv);
  }
  maskbits_k<<<(CT * 64 + 255) / 256, 256, 0, stream>>>(MSK, mbits);

  // layer-0 input -> bf16 (layer 1 gets it fused from FFN2's reduce)
  {
    int n4 = BT_ * CD / 4;
    f32_to_bf16_k<<<(n4 + 255) / 256, 256, 0, stream>>>(X, xb, n4);
  }

  for (int l = 0; l < CL; ++l) {
    const float* xcur = (l == 0) ? X : xf;
    // QKV projection: (4096x768) @ (768x2304) + bias -> qkv bf16
    gemm_k<EPI_BIAS_BF16><<<dim3(2304 / 128, BT_ / 128), 256, 0, stream>>>(
        xb, CD, wqkv_t + (size_t)l * 2304 * CD, CD, qkv, 2304, CD,
        bqkv + (size_t)l * 2304, nullptr, nullptr);
    // V transpose + fused flash attention
    vtrans_k<<<dim3(CT / 64, CB * CH), 256, 0, stream>>>(qkv, vt);
    flash_k<<<dim3(CT / 64, CB * CH), 256, 0, stream>>>(qkv, vt, mbits, attno);
    // output projection + bias + residual -> xattn (fp32)
    gemm_k<EPI_BIAS_RES_F32><<<dim3(CD / 128, BT_ / 128), 256, 0, stream>>>(
        attno, CD, wo_t + (size_t)l * CD * CD, CD, xattn, CD, CD,
        bo + (size_t)l * CD, xcur, nullptr);
    // layernorm -> hln bf16
    ln_k<<<BT_, 256, 0, stream>>>(xattn, hln, lng + (size_t)l * CD, lnb + (size_t)l * CD);
    // FFN1 + bias + gelu -> gbuf bf16
    gemm_k<EPI_BIAS_GELU_BF16><<<dim3(CF / 128, BT_ / 128), 256, 0, stream>>>(
        hln, CD, w1_t + (size_t)l * CF * CD, CD, gbuf, CF, CD,
        b1 + (size_t)l * CF, nullptr, nullptr);
    // FFN2 split-K=2 (fills the 192-block grid hole) -> f32 partials
    gemm_k<EPI_PART_F32><<<dim3(CD / 128, BT_ / 128, 2), 256, 0, stream>>>(
        gbuf, CF, w2_t + (size_t)l * CD * CF, CF, part, CD, CF / 2,
        nullptr, nullptr, nullptr);
    // reduce partials + bias + residual -> xf (+ bf16 xb) or d_out
    const int nred = BT_ * CD / 4 / 256;  // 3072 blocks
    if (l == CL - 1) {
      reduce2_k<false><<<nred, 256, 0, stream>>>(part, b2 + (size_t)l * CD, xattn,
                                                 (float*)d_out, nullptr);
    } else {
      reduce2_k<true><<<nred, 256, 0, stream>>>(part, b2 + (size_t)l * CD, xattn,
                                                xf, xb);
    }
  }
}